// Round 1
// baseline (7199.681 us; speedup 1.0000x reference)
//
#include <hip/hip_runtime.h>

#define NNODES 100000
#define NEDGES 1600000
#define FIN 256
#define HDIM 256
#define CDIM 64
#define BN_EPS 1e-5f

__global__ void init_deg_k(float* __restrict__ deg, int n) {
  int i = blockIdx.x * blockDim.x + threadIdx.x;
  if (i < n) deg[i] = 1.0f;  // self-loop
}

__global__ void count_deg_k(const int* __restrict__ dst, float* __restrict__ deg, int e) {
  int i = blockIdx.x * blockDim.x + threadIdx.x;
  if (i < e) atomicAdd(&deg[dst[i]], 1.0f);
}

__global__ void dinv_k(const float* __restrict__ deg, float* __restrict__ dinv, int n) {
  int i = blockIdx.x * blockDim.x + threadIdx.x;
  if (i < n) dinv[i] = rsqrtf(deg[i]);
}

// C = A(MxK) * B(KxN), all row-major. 64x64 tile, BK=16, 256 threads, 4x4/thread.
__global__ __launch_bounds__(256) void gemm_k(const float* __restrict__ A,
                                              const float* __restrict__ B,
                                              float* __restrict__ C,
                                              int M, int N, int K) {
  __shared__ float As[16][65];  // As[k][m]
  __shared__ float Bs[16][65];  // Bs[k][n]
  int tid = threadIdx.x;
  int tx = tid & 15, ty = tid >> 4;
  int row0 = blockIdx.x * 64;
  int col0 = blockIdx.y * 64;
  float acc[4][4] = {};
  for (int k0 = 0; k0 < K; k0 += 16) {
    // load A tile 64x16 (one float4 per thread, along K)
    {
      int m = tid >> 2, kq = (tid & 3) * 4;
      int row = row0 + m;
      float4 v = make_float4(0.f, 0.f, 0.f, 0.f);
      if (row < M) v = *reinterpret_cast<const float4*>(A + (size_t)row * K + k0 + kq);
      As[kq + 0][m] = v.x; As[kq + 1][m] = v.y; As[kq + 2][m] = v.z; As[kq + 3][m] = v.w;
    }
    // load B tile 16x64
    {
      int kk = tid >> 4, c = (tid & 15) * 4;
      float4 v = *reinterpret_cast<const float4*>(B + (size_t)(k0 + kk) * N + col0 + c);
      Bs[kk][c + 0] = v.x; Bs[kk][c + 1] = v.y; Bs[kk][c + 2] = v.z; Bs[kk][c + 3] = v.w;
    }
    __syncthreads();
    #pragma unroll
    for (int k = 0; k < 16; ++k) {
      float a[4], b[4];
      #pragma unroll
      for (int i = 0; i < 4; ++i) a[i] = As[k][ty * 4 + i];
      #pragma unroll
      for (int j = 0; j < 4; ++j) b[j] = Bs[k][tx * 4 + j];
      #pragma unroll
      for (int i = 0; i < 4; ++i)
        #pragma unroll
        for (int j = 0; j < 4; ++j)
          acc[i][j] += a[i] * b[j];
    }
    __syncthreads();
  }
  #pragma unroll
  for (int i = 0; i < 4; ++i) {
    int row = row0 + ty * 4 + i;
    if (row < M) {
      #pragma unroll
      for (int j = 0; j < 4; ++j)
        C[(size_t)row * N + col0 + tx * 4 + j] = acc[i][j];
    }
  }
}

// One thread per (edge, 4-feature chunk). Gather h[src] row, scale, atomic-add into agg[dst].
template <int F>
__global__ __launch_bounds__(256) void edge_agg_k(const int* __restrict__ src,
                                                  const int* __restrict__ dstv,
                                                  const float* __restrict__ dinv,
                                                  const float* __restrict__ h,
                                                  float* __restrict__ agg, int nEdges) {
  const int CH = F / 4;
  long long idx = (long long)blockIdx.x * blockDim.x + threadIdx.x;
  long long total = (long long)nEdges * CH;
  if (idx >= total) return;
  int e = (int)(idx / CH);
  int c = (int)(idx % CH);
  int s = src[e], d = dstv[e];
  float coef = dinv[s] * dinv[d];
  float4 v = *reinterpret_cast<const float4*>(h + (size_t)s * F + c * 4);
  float* o = agg + (size_t)d * F + c * 4;
  atomicAdd(o + 0, v.x * coef);
  atomicAdd(o + 1, v.y * coef);
  atomicAdd(o + 2, v.z * coef);
  atomicAdd(o + 3, v.w * coef);
}

// h <- relu(BN(agg + h*dinv^2 + b1)), in place on h.
__global__ void combine1_k(const float* __restrict__ agg, float* __restrict__ h,
                           const float* __restrict__ dinv,
                           const float* __restrict__ b1, const float* __restrict__ gamma,
                           const float* __restrict__ beta, const float* __restrict__ rm,
                           const float* __restrict__ rv, int n) {
  long long idx = (long long)blockIdx.x * blockDim.x + threadIdx.x;
  if (idx >= (long long)n * HDIM) return;
  int i = (int)(idx >> 8);
  int f = (int)(idx & (HDIM - 1));
  float di = dinv[i];
  float v = agg[idx] + h[idx] * di * di + b1[f];
  float s = gamma[f] * rsqrtf(rv[f] + BN_EPS);
  v = (v - rm[f]) * s + beta[f];
  h[idx] = fmaxf(v, 0.0f);
}

// out <- h2*dinv^2 + b2 (then edge_agg accumulates on top)
__global__ void initout_k(const float* __restrict__ h2, const float* __restrict__ dinv,
                          const float* __restrict__ b2, float* __restrict__ out, int n) {
  long long idx = (long long)blockIdx.x * blockDim.x + threadIdx.x;
  if (idx >= (long long)n * CDIM) return;
  int i = (int)(idx >> 6);
  int f = (int)(idx & (CDIM - 1));
  float di = dinv[i];
  out[idx] = h2[idx] * di * di + b2[f];
}

extern "C" void kernel_launch(void* const* d_in, const int* in_sizes, int n_in,
                              void* d_out, int out_size, void* d_ws, size_t ws_size,
                              hipStream_t stream) {
  const float* x     = (const float*)d_in[0];
  const int*   ei    = (const int*)d_in[1];
  const float* W1    = (const float*)d_in[2];
  const float* b1    = (const float*)d_in[3];
  const float* gamma = (const float*)d_in[4];
  const float* beta  = (const float*)d_in[5];
  const float* rm    = (const float*)d_in[6];
  const float* rv    = (const float*)d_in[7];
  const float* W2    = (const float*)d_in[8];
  const float* b2    = (const float*)d_in[9];
  float* out = (float*)d_out;

  const int* src = ei;
  const int* dst = ei + NEDGES;

  char* ws = (char*)d_ws;
  float* deg  = (float*)ws; ws += (((size_t)NNODES * 4) + 255) & ~(size_t)255;
  float* dinv = (float*)ws; ws += (((size_t)NNODES * 4) + 255) & ~(size_t)255;
  float* h    = (float*)ws; ws += (size_t)NNODES * HDIM * 4;
  float* agg1 = (float*)ws; ws += (size_t)NNODES * HDIM * 4;
  float* h2   = (float*)ws; ws += (size_t)NNODES * CDIM * 4;

  hipMemsetAsync(agg1, 0, (size_t)NNODES * HDIM * 4, stream);
  init_deg_k<<<(NNODES + 255) / 256, 256, 0, stream>>>(deg, NNODES);
  count_deg_k<<<(NEDGES + 255) / 256, 256, 0, stream>>>(dst, deg, NEDGES);
  dinv_k<<<(NNODES + 255) / 256, 256, 0, stream>>>(deg, dinv, NNODES);

  // conv1: h = x @ W1
  gemm_k<<<dim3((NNODES + 63) / 64, HDIM / 64), 256, 0, stream>>>(x, W1, h, NNODES, HDIM, FIN);
  {
    long long tot = (long long)NEDGES * (HDIM / 4);
    edge_agg_k<HDIM><<<(int)((tot + 255) / 256), 256, 0, stream>>>(src, dst, dinv, h, agg1, NEDGES);
  }
  {
    long long tot = (long long)NNODES * HDIM;
    combine1_k<<<(int)((tot + 255) / 256), 256, 0, stream>>>(agg1, h, dinv, b1, gamma, beta, rm, rv, NNODES);
  }

  // conv2: h2 = h @ W2
  gemm_k<<<dim3((NNODES + 63) / 64, CDIM / 64), 256, 0, stream>>>(h, W2, h2, NNODES, CDIM, HDIM);
  {
    long long tot = (long long)NNODES * CDIM;
    initout_k<<<(int)((tot + 255) / 256), 256, 0, stream>>>(h2, dinv, b2, out, NNODES);
  }
  {
    long long tot = (long long)NEDGES * (CDIM / 4);
    edge_agg_k<CDIM><<<(int)((tot + 255) / 256), 256, 0, stream>>>(src, dst, dinv, h2, out, NEDGES);
  }
}

// Round 2
// 1097.446 us; speedup vs baseline: 6.5604x; 6.5604x over previous
//
#include <hip/hip_runtime.h>

#define NNODES 100000
#define NEDGES 1600000
#define FIN 256
#define HDIM 256
#define CDIM 64
#define BN_EPS 1e-5f

// ---------- degree / CSR build ----------

__global__ void hist_k(const int* __restrict__ dst, int* __restrict__ cnt, int e) {
  int i = blockIdx.x * blockDim.x + threadIdx.x;
  if (i < e) atomicAdd(&cnt[dst[i]], 1);
}

__global__ void dinv_k(const int* __restrict__ cnt, float* __restrict__ dinv, int n) {
  int i = blockIdx.x * blockDim.x + threadIdx.x;
  if (i < n) dinv[i] = rsqrtf((float)cnt[i] + 1.0f);  // +1 self-loop
}

// single-block exclusive scan of cnt[0..n) -> ptr, cursor. 1024 threads.
__global__ __launch_bounds__(1024) void scan_k(const int* __restrict__ cnt,
                                               int* __restrict__ ptr,
                                               int* __restrict__ cursor, int n) {
  __shared__ int smem[1024];
  __shared__ int running;
  if (threadIdx.x == 0) running = 0;
  __syncthreads();
  for (int base = 0; base < n; base += 1024) {
    int i = base + (int)threadIdx.x;
    int v = (i < n) ? cnt[i] : 0;
    smem[threadIdx.x] = v;
    __syncthreads();
    #pragma unroll
    for (int off = 1; off < 1024; off <<= 1) {
      int t = (threadIdx.x >= off) ? smem[threadIdx.x - off] : 0;
      __syncthreads();
      smem[threadIdx.x] += t;
      __syncthreads();
    }
    int excl = smem[threadIdx.x] - v + running;
    if (i < n) { ptr[i] = excl; cursor[i] = excl; }
    __syncthreads();
    if (threadIdx.x == 1023) running += smem[1023];
    __syncthreads();
  }
  if (threadIdx.x == 0) ptr[n] = running;
}

__global__ void scatter_k(const int* __restrict__ src, const int* __restrict__ dst,
                          int* __restrict__ cursor, int* __restrict__ s_sorted, int e) {
  int i = blockIdx.x * blockDim.x + threadIdx.x;
  if (i < e) {
    int d = dst[i];
    int pos = atomicAdd(&cursor[d], 1);
    s_sorted[pos] = src[i];
  }
}

// ---------- GEMM: C = A(MxK) * B(KxN), row-major. 64x64 tile, BK=16 ----------

__global__ __launch_bounds__(256) void gemm_k(const float* __restrict__ A,
                                              const float* __restrict__ B,
                                              float* __restrict__ C,
                                              int M, int N, int K) {
  __shared__ float As[16][65];
  __shared__ float Bs[16][65];
  int tid = threadIdx.x;
  int tx = tid & 15, ty = tid >> 4;
  int row0 = blockIdx.x * 64;
  int col0 = blockIdx.y * 64;
  float acc[4][4] = {};
  for (int k0 = 0; k0 < K; k0 += 16) {
    {
      int m = tid >> 2, kq = (tid & 3) * 4;
      int row = row0 + m;
      float4 v = make_float4(0.f, 0.f, 0.f, 0.f);
      if (row < M) v = *reinterpret_cast<const float4*>(A + (size_t)row * K + k0 + kq);
      As[kq + 0][m] = v.x; As[kq + 1][m] = v.y; As[kq + 2][m] = v.z; As[kq + 3][m] = v.w;
    }
    {
      int kk = tid >> 4, c = (tid & 15) * 4;
      float4 v = *reinterpret_cast<const float4*>(B + (size_t)(k0 + kk) * N + col0 + c);
      Bs[kk][c + 0] = v.x; Bs[kk][c + 1] = v.y; Bs[kk][c + 2] = v.z; Bs[kk][c + 3] = v.w;
    }
    __syncthreads();
    #pragma unroll
    for (int k = 0; k < 16; ++k) {
      float a[4], b[4];
      #pragma unroll
      for (int i = 0; i < 4; ++i) a[i] = As[k][ty * 4 + i];
      #pragma unroll
      for (int j = 0; j < 4; ++j) b[j] = Bs[k][tx * 4 + j];
      #pragma unroll
      for (int i = 0; i < 4; ++i)
        #pragma unroll
        for (int j = 0; j < 4; ++j)
          acc[i][j] += a[i] * b[j];
    }
    __syncthreads();
  }
  #pragma unroll
  for (int i = 0; i < 4; ++i) {
    int row = row0 + ty * 4 + i;
    if (row < M) {
      #pragma unroll
      for (int j = 0; j < 4; ++j)
        C[(size_t)row * N + col0 + tx * 4 + j] = acc[i][j];
    }
  }
}

// ---------- fused aggregation 1: wave per node, float4 per lane (256 feats) ----------
// hout[i] = relu(BN(sum_e coef*h[src_e] + h[i]*dinv^2 + b1))

__global__ __launch_bounds__(256) void agg1_fused_k(
    const int* __restrict__ ptr, const int* __restrict__ ss,
    const float* __restrict__ dinv, const float* __restrict__ h,
    const float* __restrict__ b1, const float* __restrict__ gamma,
    const float* __restrict__ beta, const float* __restrict__ rm,
    const float* __restrict__ rv, float* __restrict__ hout, int n) {
  int w = threadIdx.x >> 6;
  int lane = threadIdx.x & 63;
  int i = blockIdx.x * 4 + w;
  if (i >= n) return;
  int beg = ptr[i], end = ptr[i + 1];
  float di = dinv[i];
  float4 acc = make_float4(0.f, 0.f, 0.f, 0.f);
  for (int e = beg; e < end; ++e) {
    int s = ss[e];
    float c = dinv[s] * di;
    float4 v = *reinterpret_cast<const float4*>(h + (size_t)s * HDIM + lane * 4);
    acc.x += v.x * c; acc.y += v.y * c; acc.z += v.z * c; acc.w += v.w * c;
  }
  float di2 = di * di;
  float4 hs = *reinterpret_cast<const float4*>(h + (size_t)i * HDIM + lane * 4);
  acc.x += hs.x * di2; acc.y += hs.y * di2; acc.z += hs.z * di2; acc.w += hs.w * di2;
  int f0 = lane * 4;
  float4 vb1 = *reinterpret_cast<const float4*>(b1 + f0);
  float4 vg  = *reinterpret_cast<const float4*>(gamma + f0);
  float4 vbe = *reinterpret_cast<const float4*>(beta + f0);
  float4 vrm = *reinterpret_cast<const float4*>(rm + f0);
  float4 vrv = *reinterpret_cast<const float4*>(rv + f0);
  float4 o;
  {
    float s0 = vg.x * rsqrtf(vrv.x + BN_EPS);
    o.x = fmaxf((acc.x + vb1.x - vrm.x) * s0 + vbe.x, 0.f);
    float s1 = vg.y * rsqrtf(vrv.y + BN_EPS);
    o.y = fmaxf((acc.y + vb1.y - vrm.y) * s1 + vbe.y, 0.f);
    float s2 = vg.z * rsqrtf(vrv.z + BN_EPS);
    o.z = fmaxf((acc.z + vb1.z - vrm.z) * s2 + vbe.z, 0.f);
    float s3 = vg.w * rsqrtf(vrv.w + BN_EPS);
    o.w = fmaxf((acc.w + vb1.w - vrm.w) * s3 + vbe.w, 0.f);
  }
  *reinterpret_cast<float4*>(hout + (size_t)i * HDIM + f0) = o;
}

// ---------- fused aggregation 2: wave per node, scalar per lane (64 feats) ----------
// out[i] = sum_e coef*h2[src_e] + h2[i]*dinv^2 + b2

__global__ __launch_bounds__(256) void agg2_fused_k(
    const int* __restrict__ ptr, const int* __restrict__ ss,
    const float* __restrict__ dinv, const float* __restrict__ h2,
    const float* __restrict__ b2, float* __restrict__ out, int n) {
  int w = threadIdx.x >> 6;
  int lane = threadIdx.x & 63;
  int i = blockIdx.x * 4 + w;
  if (i >= n) return;
  int beg = ptr[i], end = ptr[i + 1];
  float di = dinv[i];
  float acc = 0.f;
  for (int e = beg; e < end; ++e) {
    int s = ss[e];
    acc += dinv[s] * di * h2[(size_t)s * CDIM + lane];
  }
  acc += h2[(size_t)i * CDIM + lane] * di * di + b2[lane];
  out[(size_t)i * CDIM + lane] = acc;
}

extern "C" void kernel_launch(void* const* d_in, const int* in_sizes, int n_in,
                              void* d_out, int out_size, void* d_ws, size_t ws_size,
                              hipStream_t stream) {
  const float* x     = (const float*)d_in[0];
  const int*   ei    = (const int*)d_in[1];
  const float* W1    = (const float*)d_in[2];
  const float* b1    = (const float*)d_in[3];
  const float* gamma = (const float*)d_in[4];
  const float* beta  = (const float*)d_in[5];
  const float* rm    = (const float*)d_in[6];
  const float* rv    = (const float*)d_in[7];
  const float* W2    = (const float*)d_in[8];
  const float* b2    = (const float*)d_in[9];
  float* out = (float*)d_out;

  const int* src = ei;
  const int* dst = ei + NEDGES;

  char* ws = (char*)d_ws;
  auto alloc = [&](size_t bytes) {
    void* p = ws;
    ws += (bytes + 255) & ~(size_t)255;
    return p;
  };
  int*   cnt      = (int*)alloc((size_t)NNODES * 4);
  int*   ptr      = (int*)alloc(((size_t)NNODES + 1) * 4);
  int*   cursor   = (int*)alloc((size_t)NNODES * 4);
  float* dinv     = (float*)alloc((size_t)NNODES * 4);
  int*   s_sorted = (int*)alloc((size_t)NEDGES * 4);
  float* h        = (float*)alloc((size_t)NNODES * HDIM * 4);
  float* hout     = (float*)alloc((size_t)NNODES * HDIM * 4);
  float* h2       = (float*)alloc((size_t)NNODES * CDIM * 4);

  // CSR build
  hipMemsetAsync(cnt, 0, (size_t)NNODES * 4, stream);
  hist_k<<<(NEDGES + 255) / 256, 256, 0, stream>>>(dst, cnt, NEDGES);
  dinv_k<<<(NNODES + 255) / 256, 256, 0, stream>>>(cnt, dinv, NNODES);
  scan_k<<<1, 1024, 0, stream>>>(cnt, ptr, cursor, NNODES);
  scatter_k<<<(NEDGES + 255) / 256, 256, 0, stream>>>(src, dst, cursor, s_sorted, NEDGES);

  // conv1: h = x @ W1
  gemm_k<<<dim3((NNODES + 63) / 64, HDIM / 64), 256, 0, stream>>>(x, W1, h, NNODES, HDIM, FIN);
  agg1_fused_k<<<(NNODES + 3) / 4, 256, 0, stream>>>(ptr, s_sorted, dinv, h,
                                                     b1, gamma, beta, rm, rv, hout, NNODES);

  // conv2: h2 = hout @ W2
  gemm_k<<<dim3((NNODES + 63) / 64, CDIM / 64), 256, 0, stream>>>(hout, W2, h2, NNODES, CDIM, HDIM);
  agg2_fused_k<<<(NNODES + 3) / 4, 256, 0, stream>>>(ptr, s_sorted, dinv, h2, b2, out, NNODES);
}

// Round 3
// 640.453 us; speedup vs baseline: 11.2415x; 1.7135x over previous
//
#include <hip/hip_runtime.h>

#define NNODES 100000
#define NEDGES 1600000
#define FIN 256
#define HDIM 256
#define CDIM 64
#define BN_EPS 1e-5f

typedef __attribute__((ext_vector_type(8))) short short8;
typedef __attribute__((ext_vector_type(4))) float f32x4;

static __device__ __forceinline__ unsigned short f2bf(float f) {
  unsigned u = __float_as_uint(f);
  u += 0x7FFF + ((u >> 16) & 1);
  return (unsigned short)(u >> 16);
}
static __device__ __forceinline__ float bf2f(unsigned short h) {
  return __uint_as_float(((unsigned)h) << 16);
}

// ---------- degree / CSR build ----------

__global__ void hist_k(const int* __restrict__ dst, int* __restrict__ cnt, int e) {
  int i = blockIdx.x * blockDim.x + threadIdx.x;
  if (i < e) atomicAdd(&cnt[dst[i]], 1);
}

__global__ void dinv_k(const int* __restrict__ cnt, float* __restrict__ dinv, int n) {
  int i = blockIdx.x * blockDim.x + threadIdx.x;
  if (i < n) dinv[i] = rsqrtf((float)cnt[i] + 1.0f);
}

// parallel scan: per-block (512-chunk) sums
__global__ __launch_bounds__(256) void partial_k(const int* __restrict__ cnt,
                                                 int* __restrict__ partial, int n) {
  int base = blockIdx.x * 512;
  int s = 0;
  for (int i = threadIdx.x; i < 512; i += 256) {
    int g = base + i;
    if (g < n) s += cnt[g];
  }
  #pragma unroll
  for (int off = 32; off > 0; off >>= 1) s += __shfl_down(s, off, 64);
  __shared__ int red[4];
  if ((threadIdx.x & 63) == 0) red[threadIdx.x >> 6] = s;
  __syncthreads();
  if (threadIdx.x == 0) partial[blockIdx.x] = red[0] + red[1] + red[2] + red[3];
}

// single small block: exclusive scan of <=256 partials
__global__ __launch_bounds__(256) void scanpart_k(const int* __restrict__ partial,
                                                  int* __restrict__ pscan, int nb) {
  __shared__ int sm[256];
  int t = threadIdx.x;
  int v = (t < nb) ? partial[t] : 0;
  sm[t] = v;
  __syncthreads();
  for (int off = 1; off < 256; off <<= 1) {
    int x = (t >= off) ? sm[t - off] : 0;
    __syncthreads();
    sm[t] += x;
    __syncthreads();
  }
  if (t < nb) pscan[t] = sm[t] - v;
}

__global__ __launch_bounds__(256) void apply_k(const int* __restrict__ cnt,
                                               const int* __restrict__ pscan,
                                               int* __restrict__ ptr,
                                               int* __restrict__ cursor, int n) {
  __shared__ int wsum[4];
  int tid = threadIdx.x, lane = tid & 63, w = tid >> 6;
  int base = blockIdx.x * 512;
  int running = pscan[blockIdx.x];
  for (int rp = 0; rp < 2; ++rp) {
    int i = base + rp * 256 + tid;
    int v = (i < n) ? cnt[i] : 0;
    int x = v;
    #pragma unroll
    for (int off = 1; off < 64; off <<= 1) {
      int t = __shfl_up(x, off, 64);
      if (lane >= off) x += t;
    }
    if (lane == 63) wsum[w] = x;
    __syncthreads();
    int wb = 0;
    for (int j = 0; j < w; ++j) wb += wsum[j];
    int excl = running + wb + x - v;
    if (i < n) { ptr[i] = excl; cursor[i] = excl; }
    int tot = wsum[0] + wsum[1] + wsum[2] + wsum[3];
    __syncthreads();
    running += tot;
  }
  if (blockIdx.x == 0 && tid == 0) ptr[n] = NEDGES;
}

__global__ void scatter_k(const int* __restrict__ src, const int* __restrict__ dst,
                          int* __restrict__ cursor, int* __restrict__ s_sorted, int e) {
  int i = blockIdx.x * blockDim.x + threadIdx.x;
  if (i < e) {
    int d = dst[i];
    int pos = atomicAdd(&cursor[d], 1);
    s_sorted[pos] = src[i];
  }
}

// ---------- fp32 -> bf16 hi/lo split ----------

__global__ void split_x_k(const float* __restrict__ x, unsigned short* __restrict__ hi,
                          unsigned short* __restrict__ lo, int n4) {
  int i = blockIdx.x * blockDim.x + threadIdx.x;
  int stride = gridDim.x * blockDim.x;
  for (; i < n4; i += stride) {
    float4 v = reinterpret_cast<const float4*>(x)[i];
    unsigned short h0 = f2bf(v.x), h1 = f2bf(v.y), h2 = f2bf(v.z), h3 = f2bf(v.w);
    ushort4 H = make_ushort4(h0, h1, h2, h3);
    ushort4 L = make_ushort4(f2bf(v.x - bf2f(h0)), f2bf(v.y - bf2f(h1)),
                             f2bf(v.z - bf2f(h2)), f2bf(v.w - bf2f(h3)));
    reinterpret_cast<ushort4*>(hi)[i] = H;
    reinterpret_cast<ushort4*>(lo)[i] = L;
  }
}

// W[K][N] fp32 -> Wt[N][K] bf16 hi/lo (tiny)
__global__ void split_wt_k(const float* __restrict__ W, unsigned short* __restrict__ hi,
                           unsigned short* __restrict__ lo, int K, int N) {
  int n = blockIdx.x;
  for (int k = threadIdx.x; k < K; k += blockDim.x) {
    float v = W[(size_t)k * N + n];
    unsigned short h = f2bf(v);
    hi[(size_t)n * K + k] = h;
    lo[(size_t)n * K + k] = f2bf(v - bf2f(h));
  }
}

// ---------- split-bf16 MFMA GEMM: C = A*Bt^T (A[M][K], Bt[N][K], C[M][N]) ----------
// 3-term: Ahi*Bhi + Ahi*Blo + Alo*Bhi, fp32 accum. BM=128, BK=64.

template <int BN>
__global__ __launch_bounds__(256) void gemm_split_k(
    const unsigned short* __restrict__ Ahi, const unsigned short* __restrict__ Alo,
    const unsigned short* __restrict__ Bhi, const unsigned short* __restrict__ Blo,
    float* __restrict__ C, int M, int N, int K) {
  constexpr int WC = BN / 32;  // 16x16 frags per wave along N
  __shared__ unsigned short smem[2 * 128 * 64 + 2 * BN * 64];
  unsigned short* aHi = smem;
  unsigned short* aLo = smem + 128 * 64;
  unsigned short* bHi = smem + 2 * 128 * 64;
  unsigned short* bLo = bHi + BN * 64;

  const int tid = threadIdx.x;
  const int w = tid >> 6;
  const int lane = tid & 63;
  const int wr = w >> 1, wc = w & 1;
  const int row0 = blockIdx.x * 128;
  const int col0 = blockIdx.y * BN;

  f32x4 acc[4][WC];
  #pragma unroll
  for (int mi = 0; mi < 4; ++mi)
    #pragma unroll
    for (int ni = 0; ni < WC; ++ni) {
      f32x4 z = {0.f, 0.f, 0.f, 0.f};
      acc[mi][ni] = z;
    }

  // stage: rows x 64 bf16 tile; linear LDS dest, XOR-swizzled global source (rule #21)
  auto stage = [&](const unsigned short* G, unsigned short* Ld, int rows, int gr0,
                   int maxRow, int k0) {
    for (int i = 0; i < rows / 32; ++i) {
      int chunk = i * 256 + tid;  // 16B chunk
      int r = chunk >> 3;
      int c = chunk & 7;
      int cs = c ^ (r & 7);
      int gr = gr0 + r;
      if (gr > maxRow) gr = maxRow;
      const unsigned short* gp = G + (size_t)gr * K + k0 + cs * 8;
      unsigned short* lp = Ld + (i * 256 + w * 64) * 8;  // wave-uniform base
      __builtin_amdgcn_global_load_lds((const __attribute__((address_space(1))) void*)gp,
                                       (__attribute__((address_space(3))) void*)lp, 16, 0, 0);
    }
  };

  for (int k0 = 0; k0 < K; k0 += 64) {
    stage(Ahi, aHi, 128, row0, M - 1, k0);
    stage(Alo, aLo, 128, row0, M - 1, k0);
    stage(Bhi, bHi, BN, col0, N - 1, k0);
    stage(Blo, bLo, BN, col0, N - 1, k0);
    __syncthreads();
    #pragma unroll
    for (int kk = 0; kk < 2; ++kk) {
      short8 ah[4], al[4], bh[WC], bl[WC];
      #pragma unroll
      for (int mi = 0; mi < 4; ++mi) {
        int lr = wr * 64 + mi * 16 + (lane & 15);
        int slot = (kk * 4 + (lane >> 4)) ^ (lr & 7);
        int eo = lr * 64 + slot * 8;
        ah[mi] = *reinterpret_cast<const short8*>(aHi + eo);
        al[mi] = *reinterpret_cast<const short8*>(aLo + eo);
      }
      #pragma unroll
      for (int ni = 0; ni < WC; ++ni) {
        int lr = wc * (BN / 2) + ni * 16 + (lane & 15);
        int slot = (kk * 4 + (lane >> 4)) ^ (lr & 7);
        int eo = lr * 64 + slot * 8;
        bh[ni] = *reinterpret_cast<const short8*>(bHi + eo);
        bl[ni] = *reinterpret_cast<const short8*>(bLo + eo);
      }
      #pragma unroll
      for (int mi = 0; mi < 4; ++mi)
        #pragma unroll
        for (int ni = 0; ni < WC; ++ni) {
          acc[mi][ni] = __builtin_amdgcn_mfma_f32_16x16x32_bf16(ah[mi], bh[ni], acc[mi][ni], 0, 0, 0);
          acc[mi][ni] = __builtin_amdgcn_mfma_f32_16x16x32_bf16(ah[mi], bl[ni], acc[mi][ni], 0, 0, 0);
          acc[mi][ni] = __builtin_amdgcn_mfma_f32_16x16x32_bf16(al[mi], bh[ni], acc[mi][ni], 0, 0, 0);
        }
    }
    __syncthreads();
  }

  // C/D layout: col = lane&15, row = (lane>>4)*4 + r  [m89-verified]
  #pragma unroll
  for (int mi = 0; mi < 4; ++mi) {
    int rbase = row0 + wr * 64 + mi * 16 + (lane >> 4) * 4;
    #pragma unroll
    for (int ni = 0; ni < WC; ++ni) {
      int cc = col0 + wc * (BN / 2) + ni * 16 + (lane & 15);
      #pragma unroll
      for (int r = 0; r < 4; ++r) {
        int rr = rbase + r;
        if (rr < M) C[(size_t)rr * N + cc] = acc[mi][ni][r];
      }
    }
  }
}

// ---------- fused aggregation 1 (256 feats), writes bf16 hi/lo for GEMM2 ----------

__global__ __launch_bounds__(256) void agg1_fused_k(
    const int* __restrict__ ptr, const int* __restrict__ ss,
    const float* __restrict__ dinv, const float* __restrict__ h,
    const float* __restrict__ b1, const float* __restrict__ gamma,
    const float* __restrict__ beta, const float* __restrict__ rm,
    const float* __restrict__ rv, unsigned short* __restrict__ hHi,
    unsigned short* __restrict__ hLo, int n) {
  int w = threadIdx.x >> 6;
  int lane = threadIdx.x & 63;
  int i = blockIdx.x * 4 + w;
  if (i >= n) return;
  int beg = ptr[i], end = ptr[i + 1];
  float di = dinv[i];
  int f0 = lane * 4;
  float ax = 0.f, ay = 0.f, az = 0.f, aw = 0.f;
  int e = beg;
  for (; e + 4 <= end; e += 4) {
    int s0 = ss[e], s1 = ss[e + 1], s2 = ss[e + 2], s3 = ss[e + 3];
    float c0 = dinv[s0], c1 = dinv[s1], c2 = dinv[s2], c3 = dinv[s3];
    float4 v0 = *reinterpret_cast<const float4*>(h + (size_t)s0 * HDIM + f0);
    float4 v1 = *reinterpret_cast<const float4*>(h + (size_t)s1 * HDIM + f0);
    float4 v2 = *reinterpret_cast<const float4*>(h + (size_t)s2 * HDIM + f0);
    float4 v3 = *reinterpret_cast<const float4*>(h + (size_t)s3 * HDIM + f0);
    ax += c0 * v0.x + c1 * v1.x + c2 * v2.x + c3 * v3.x;
    ay += c0 * v0.y + c1 * v1.y + c2 * v2.y + c3 * v3.y;
    az += c0 * v0.z + c1 * v1.z + c2 * v2.z + c3 * v3.z;
    aw += c0 * v0.w + c1 * v1.w + c2 * v2.w + c3 * v3.w;
  }
  for (; e < end; ++e) {
    int s = ss[e];
    float c = dinv[s];
    float4 v = *reinterpret_cast<const float4*>(h + (size_t)s * HDIM + f0);
    ax += c * v.x; ay += c * v.y; az += c * v.z; aw += c * v.w;
  }
  float di2 = di * di;
  float4 hs = *reinterpret_cast<const float4*>(h + (size_t)i * HDIM + f0);
  float4 vb1 = *reinterpret_cast<const float4*>(b1 + f0);
  float4 vg  = *reinterpret_cast<const float4*>(gamma + f0);
  float4 vbe = *reinterpret_cast<const float4*>(beta + f0);
  float4 vrm = *reinterpret_cast<const float4*>(rm + f0);
  float4 vrv = *reinterpret_cast<const float4*>(rv + f0);
  float o0 = fmaxf((ax * di + hs.x * di2 + vb1.x - vrm.x) * (vg.x * rsqrtf(vrv.x + BN_EPS)) + vbe.x, 0.f);
  float o1 = fmaxf((ay * di + hs.y * di2 + vb1.y - vrm.y) * (vg.y * rsqrtf(vrv.y + BN_EPS)) + vbe.y, 0.f);
  float o2 = fmaxf((az * di + hs.z * di2 + vb1.z - vrm.z) * (vg.z * rsqrtf(vrv.z + BN_EPS)) + vbe.z, 0.f);
  float o3 = fmaxf((aw * di + hs.w * di2 + vb1.w - vrm.w) * (vg.w * rsqrtf(vrv.w + BN_EPS)) + vbe.w, 0.f);
  unsigned short h0 = f2bf(o0), h1 = f2bf(o1), h2 = f2bf(o2), h3 = f2bf(o3);
  ushort4 H = make_ushort4(h0, h1, h2, h3);
  ushort4 L = make_ushort4(f2bf(o0 - bf2f(h0)), f2bf(o1 - bf2f(h1)),
                           f2bf(o2 - bf2f(h2)), f2bf(o3 - bf2f(h3)));
  *reinterpret_cast<ushort4*>(hHi + (size_t)i * HDIM + f0) = H;
  *reinterpret_cast<ushort4*>(hLo + (size_t)i * HDIM + f0) = L;
}

// ---------- fused aggregation 2 (64 feats) -> out ----------

__global__ __launch_bounds__(256) void agg2_fused_k(
    const int* __restrict__ ptr, const int* __restrict__ ss,
    const float* __restrict__ dinv, const float* __restrict__ h2,
    const float* __restrict__ b2, float* __restrict__ out, int n) {
  int w = threadIdx.x >> 6;
  int lane = threadIdx.x & 63;
  int i = blockIdx.x * 4 + w;
  if (i >= n) return;
  int beg = ptr[i], end = ptr[i + 1];
  float di = dinv[i];
  float a = 0.f;
  int e = beg;
  for (; e + 4 <= end; e += 4) {
    int s0 = ss[e], s1 = ss[e + 1], s2 = ss[e + 2], s3 = ss[e + 3];
    float c0 = dinv[s0], c1 = dinv[s1], c2 = dinv[s2], c3 = dinv[s3];
    a += c0 * h2[(size_t)s0 * CDIM + lane] + c1 * h2[(size_t)s1 * CDIM + lane] +
         c2 * h2[(size_t)s2 * CDIM + lane] + c3 * h2[(size_t)s3 * CDIM + lane];
  }
  for (; e < end; ++e) {
    int s = ss[e];
    a += dinv[s] * h2[(size_t)s * CDIM + lane];
  }
  a = a * di + h2[(size_t)i * CDIM + lane] * di * di + b2[lane];
  out[(size_t)i * CDIM + lane] = a;
}

extern "C" void kernel_launch(void* const* d_in, const int* in_sizes, int n_in,
                              void* d_out, int out_size, void* d_ws, size_t ws_size,
                              hipStream_t stream) {
  const float* x     = (const float*)d_in[0];
  const int*   ei    = (const int*)d_in[1];
  const float* W1    = (const float*)d_in[2];
  const float* b1    = (const float*)d_in[3];
  const float* gamma = (const float*)d_in[4];
  const float* beta  = (const float*)d_in[5];
  const float* rm    = (const float*)d_in[6];
  const float* rv    = (const float*)d_in[7];
  const float* W2    = (const float*)d_in[8];
  const float* b2    = (const float*)d_in[9];
  float* out = (float*)d_out;

  const int* src = ei;
  const int* dst = ei + NEDGES;

  char* ws = (char*)d_ws;
  auto alloc = [&](size_t bytes) {
    void* p = ws;
    ws += (bytes + 255) & ~(size_t)255;
    return p;
  };
  const int NB = (NNODES + 511) / 512;  // 196
  int*   cnt      = (int*)alloc((size_t)NNODES * 4);
  int*   ptr      = (int*)alloc(((size_t)NNODES + 1) * 4);
  int*   cursor   = (int*)alloc((size_t)NNODES * 4);
  float* dinv     = (float*)alloc((size_t)NNODES * 4);
  int*   s_sorted = (int*)alloc((size_t)NEDGES * 4);
  int*   partial  = (int*)alloc((size_t)NB * 4);
  int*   pscan    = (int*)alloc((size_t)NB * 4);
  unsigned short* xhi   = (unsigned short*)alloc((size_t)NNODES * FIN * 2);
  unsigned short* xlo   = (unsigned short*)alloc((size_t)NNODES * FIN * 2);
  unsigned short* w1thi = (unsigned short*)alloc((size_t)HDIM * FIN * 2);
  unsigned short* w1tlo = (unsigned short*)alloc((size_t)HDIM * FIN * 2);
  unsigned short* w2thi = (unsigned short*)alloc((size_t)CDIM * HDIM * 2);
  unsigned short* w2tlo = (unsigned short*)alloc((size_t)CDIM * HDIM * 2);
  float* h  = (float*)alloc((size_t)NNODES * HDIM * 4);
  float* h2 = (float*)alloc((size_t)NNODES * CDIM * 4);
  // after GEMM1, x splits are dead -> reuse for hout splits (regenerated每 call)
  unsigned short* hhi = xhi;
  unsigned short* hlo = xlo;

  // CSR build
  hipMemsetAsync(cnt, 0, (size_t)NNODES * 4, stream);
  hist_k<<<(NEDGES + 255) / 256, 256, 0, stream>>>(dst, cnt, NEDGES);
  dinv_k<<<(NNODES + 255) / 256, 256, 0, stream>>>(cnt, dinv, NNODES);
  partial_k<<<NB, 256, 0, stream>>>(cnt, partial, NNODES);
  scanpart_k<<<1, 256, 0, stream>>>(partial, pscan, NB);
  apply_k<<<NB, 256, 0, stream>>>(cnt, pscan, ptr, cursor, NNODES);
  scatter_k<<<(NEDGES + 255) / 256, 256, 0, stream>>>(src, dst, cursor, s_sorted, NEDGES);

  // splits
  split_x_k<<<25000, 256, 0, stream>>>(x, xhi, xlo, NNODES * FIN / 4);
  split_wt_k<<<HDIM, 256, 0, stream>>>(W1, w1thi, w1tlo, FIN, HDIM);
  split_wt_k<<<CDIM, 256, 0, stream>>>(W2, w2thi, w2tlo, HDIM, CDIM);

  // conv1: h = x @ W1  (MFMA split)
  gemm_split_k<128><<<dim3((NNODES + 127) / 128, HDIM / 128), 256, 0, stream>>>(
      xhi, xlo, w1thi, w1tlo, h, NNODES, HDIM, FIN);
  agg1_fused_k<<<(NNODES + 3) / 4, 256, 0, stream>>>(ptr, s_sorted, dinv, h,
                                                     b1, gamma, beta, rm, rv, hhi, hlo, NNODES);

  // conv2: h2 = hout @ W2 (MFMA split)
  gemm_split_k<64><<<dim3((NNODES + 127) / 128, 1), 256, 0, stream>>>(
      hhi, hlo, w2thi, w2tlo, h2, NNODES, CDIM, HDIM);
  agg2_fused_k<<<(NNODES + 3) / 4, 256, 0, stream>>>(ptr, s_sorted, dinv, h2, b2, out, NNODES);
}

// Round 4
// 559.021 us; speedup vs baseline: 12.8791x; 1.1457x over previous
//
#include <hip/hip_runtime.h>

#define NNODES 100000
#define NEDGES 1600000
#define FIN 256
#define HDIM 256
#define CDIM 64
#define BN_EPS 1e-5f

typedef __attribute__((ext_vector_type(8))) short short8;
typedef __attribute__((ext_vector_type(4))) float f32x4;

static __device__ __forceinline__ unsigned short f2bf(float f) {
  unsigned u = __float_as_uint(f);
  u += 0x7FFF + ((u >> 16) & 1);
  return (unsigned short)(u >> 16);
}
static __device__ __forceinline__ float bf2f(unsigned short h) {
  return __uint_as_float(((unsigned)h) << 16);
}

// ---------- degree / CSR build ----------

__global__ void hist_k(const int* __restrict__ dst, int* __restrict__ cnt, int e) {
  int i = blockIdx.x * blockDim.x + threadIdx.x;
  if (i < e) atomicAdd(&cnt[dst[i]], 1);
}

__global__ void dinv_k(const int* __restrict__ cnt, float* __restrict__ dinv, int n) {
  int i = blockIdx.x * blockDim.x + threadIdx.x;
  if (i < n) dinv[i] = rsqrtf((float)cnt[i] + 1.0f);
}

__global__ __launch_bounds__(256) void partial_k(const int* __restrict__ cnt,
                                                 int* __restrict__ partial, int n) {
  int base = blockIdx.x * 512;
  int s = 0;
  for (int i = threadIdx.x; i < 512; i += 256) {
    int g = base + i;
    if (g < n) s += cnt[g];
  }
  #pragma unroll
  for (int off = 32; off > 0; off >>= 1) s += __shfl_down(s, off, 64);
  __shared__ int red[4];
  if ((threadIdx.x & 63) == 0) red[threadIdx.x >> 6] = s;
  __syncthreads();
  if (threadIdx.x == 0) partial[blockIdx.x] = red[0] + red[1] + red[2] + red[3];
}

__global__ __launch_bounds__(256) void scanpart_k(const int* __restrict__ partial,
                                                  int* __restrict__ pscan, int nb) {
  __shared__ int sm[256];
  int t = threadIdx.x;
  int v = (t < nb) ? partial[t] : 0;
  sm[t] = v;
  __syncthreads();
  for (int off = 1; off < 256; off <<= 1) {
    int x = (t >= off) ? sm[t - off] : 0;
    __syncthreads();
    sm[t] += x;
    __syncthreads();
  }
  if (t < nb) pscan[t] = sm[t] - v;
}

__global__ __launch_bounds__(256) void apply_k(const int* __restrict__ cnt,
                                               const int* __restrict__ pscan,
                                               int* __restrict__ ptr,
                                               int* __restrict__ cursor, int n) {
  __shared__ int wsum[4];
  int tid = threadIdx.x, lane = tid & 63, w = tid >> 6;
  int base = blockIdx.x * 512;
  int running = pscan[blockIdx.x];
  for (int rp = 0; rp < 2; ++rp) {
    int i = base + rp * 256 + tid;
    int v = (i < n) ? cnt[i] : 0;
    int x = v;
    #pragma unroll
    for (int off = 1; off < 64; off <<= 1) {
      int t = __shfl_up(x, off, 64);
      if (lane >= off) x += t;
    }
    if (lane == 63) wsum[w] = x;
    __syncthreads();
    int wb = 0;
    for (int j = 0; j < w; ++j) wb += wsum[j];
    int excl = running + wb + x - v;
    if (i < n) { ptr[i] = excl; cursor[i] = excl; }
    int tot = wsum[0] + wsum[1] + wsum[2] + wsum[3];
    __syncthreads();
    running += tot;
  }
  if (blockIdx.x == 0 && tid == 0) ptr[n] = NEDGES;
}

__global__ void scatter_k(const int* __restrict__ src, const int* __restrict__ dst,
                          int* __restrict__ cursor, int* __restrict__ s_sorted, int e) {
  int i = blockIdx.x * blockDim.x + threadIdx.x;
  if (i < e) {
    int d = dst[i];
    int pos = atomicAdd(&cursor[d], 1);
    s_sorted[pos] = src[i];
  }
}

// ---------- conversions / prep ----------

__global__ void xbf_k(const float* __restrict__ x, unsigned short* __restrict__ xbf, int n4) {
  int i = blockIdx.x * blockDim.x + threadIdx.x;
  int stride = gridDim.x * blockDim.x;
  for (; i < n4; i += stride) {
    float4 v = reinterpret_cast<const float4*>(x)[i];
    reinterpret_cast<ushort4*>(xbf)[i] =
        make_ushort4(f2bf(v.x), f2bf(v.y), f2bf(v.z), f2bf(v.w));
  }
}

// W[K][N] fp32 -> Wt[N][K] bf16 hi/lo (tiny)
__global__ void split_wt_k(const float* __restrict__ W, unsigned short* __restrict__ hi,
                           unsigned short* __restrict__ lo, int K, int N) {
  int n = blockIdx.x;
  for (int k = threadIdx.x; k < K; k += blockDim.x) {
    float v = W[(size_t)k * N + n];
    unsigned short h = f2bf(v);
    hi[(size_t)n * K + k] = h;
    lo[(size_t)n * K + k] = f2bf(v - bf2f(h));
  }
}

// bn_s = gamma*rsqrt(rv+eps); bn_t = (b1-rm)*bn_s + beta   (one block, HDIM threads)
__global__ void bn_prep_k(const float* __restrict__ b1, const float* __restrict__ gamma,
                          const float* __restrict__ beta, const float* __restrict__ rm,
                          const float* __restrict__ rv, float* __restrict__ bn_s,
                          float* __restrict__ bn_t) {
  int f = threadIdx.x;
  float s = gamma[f] * rsqrtf(rv[f] + BN_EPS);
  bn_s[f] = s;
  bn_t[f] = (b1[f] - rm[f]) * s + beta[f];
}

// ---------- agg_x: xhat = A_norm * x  (gather bf16 x, self from fp32 x), emits hi/lo ----------

__global__ __launch_bounds__(256) void agg_x_k(
    const int* __restrict__ ptr, const int* __restrict__ ss,
    const float* __restrict__ dinv, const unsigned short* __restrict__ xbf,
    const float* __restrict__ x, unsigned short* __restrict__ xhHi,
    unsigned short* __restrict__ xhLo, int n) {
  int w = threadIdx.x >> 6;
  int lane = threadIdx.x & 63;
  int i = blockIdx.x * 4 + w;
  if (i >= n) return;
  int beg = ptr[i], end = ptr[i + 1];
  float di = dinv[i];
  int f0 = lane * 4;
  float ax = 0.f, ay = 0.f, az = 0.f, aw = 0.f;
  int e = beg;
  for (; e + 8 <= end; e += 8) {
    int s[8];
    float c[8];
    ushort4 v[8];
    #pragma unroll
    for (int j = 0; j < 8; ++j) s[j] = ss[e + j];
    #pragma unroll
    for (int j = 0; j < 8; ++j) {
      c[j] = dinv[s[j]];
      v[j] = *reinterpret_cast<const ushort4*>(xbf + (size_t)s[j] * FIN + f0);
    }
    #pragma unroll
    for (int j = 0; j < 8; ++j) {
      ax += c[j] * bf2f(v[j].x);
      ay += c[j] * bf2f(v[j].y);
      az += c[j] * bf2f(v[j].z);
      aw += c[j] * bf2f(v[j].w);
    }
  }
  for (; e < end; ++e) {
    int s = ss[e];
    float c = dinv[s];
    ushort4 v = *reinterpret_cast<const ushort4*>(xbf + (size_t)s * FIN + f0);
    ax += c * bf2f(v.x); ay += c * bf2f(v.y); az += c * bf2f(v.z); aw += c * bf2f(v.w);
  }
  float di2 = di * di;
  float4 xs = *reinterpret_cast<const float4*>(x + (size_t)i * FIN + f0);
  ax = ax * di + xs.x * di2;
  ay = ay * di + xs.y * di2;
  az = az * di + xs.z * di2;
  aw = aw * di + xs.w * di2;
  unsigned short h0 = f2bf(ax), h1 = f2bf(ay), h2 = f2bf(az), h3 = f2bf(aw);
  *reinterpret_cast<ushort4*>(xhHi + (size_t)i * FIN + f0) = make_ushort4(h0, h1, h2, h3);
  *reinterpret_cast<ushort4*>(xhLo + (size_t)i * FIN + f0) =
      make_ushort4(f2bf(ax - bf2f(h0)), f2bf(ay - bf2f(h1)),
                   f2bf(az - bf2f(h2)), f2bf(aw - bf2f(h3)));
}

// ---------- split-bf16 MFMA GEMM: C = A*Bt^T. BM=128, BK=64. ----------
// EPI=1: hout = relu(v*bn_s+bn_t) -> write bf16 hi/lo (GEMM1)
// EPI=2: write fp32 C and bf16(C) (GEMM2)

template <int BN, int EPI>
__global__ __launch_bounds__(256) void gemm_split_k(
    const unsigned short* __restrict__ Ahi, const unsigned short* __restrict__ Alo,
    const unsigned short* __restrict__ Bhi, const unsigned short* __restrict__ Blo,
    float* __restrict__ C, unsigned short* __restrict__ O1,
    unsigned short* __restrict__ O2, const float* __restrict__ bn_s,
    const float* __restrict__ bn_t, int M, int N, int K) {
  constexpr int WC = BN / 32;
  __shared__ unsigned short smem[2 * 128 * 64 + 2 * BN * 64];
  unsigned short* aHi = smem;
  unsigned short* aLo = smem + 128 * 64;
  unsigned short* bHi = smem + 2 * 128 * 64;
  unsigned short* bLo = bHi + BN * 64;

  const int tid = threadIdx.x;
  const int w = tid >> 6;
  const int lane = tid & 63;
  const int wr = w >> 1, wc = w & 1;
  const int row0 = blockIdx.x * 128;
  const int col0 = blockIdx.y * BN;

  f32x4 acc[4][WC];
  #pragma unroll
  for (int mi = 0; mi < 4; ++mi)
    #pragma unroll
    for (int ni = 0; ni < WC; ++ni) {
      f32x4 z = {0.f, 0.f, 0.f, 0.f};
      acc[mi][ni] = z;
    }

  auto stage = [&](const unsigned short* G, unsigned short* Ld, int rows, int gr0,
                   int maxRow, int k0) {
    for (int i = 0; i < rows / 32; ++i) {
      int chunk = i * 256 + tid;
      int r = chunk >> 3;
      int c = chunk & 7;
      int cs = c ^ (r & 7);
      int gr = gr0 + r;
      if (gr > maxRow) gr = maxRow;
      const unsigned short* gp = G + (size_t)gr * K + k0 + cs * 8;
      unsigned short* lp = Ld + (i * 256 + w * 64) * 8;
      __builtin_amdgcn_global_load_lds((const __attribute__((address_space(1))) void*)gp,
                                       (__attribute__((address_space(3))) void*)lp, 16, 0, 0);
    }
  };

  for (int k0 = 0; k0 < K; k0 += 64) {
    stage(Ahi, aHi, 128, row0, M - 1, k0);
    stage(Alo, aLo, 128, row0, M - 1, k0);
    stage(Bhi, bHi, BN, col0, N - 1, k0);
    stage(Blo, bLo, BN, col0, N - 1, k0);
    __syncthreads();
    #pragma unroll
    for (int kk = 0; kk < 2; ++kk) {
      short8 ah[4], al[4], bh[WC], bl[WC];
      #pragma unroll
      for (int mi = 0; mi < 4; ++mi) {
        int lr = wr * 64 + mi * 16 + (lane & 15);
        int slot = (kk * 4 + (lane >> 4)) ^ (lr & 7);
        int eo = lr * 64 + slot * 8;
        ah[mi] = *reinterpret_cast<const short8*>(aHi + eo);
        al[mi] = *reinterpret_cast<const short8*>(aLo + eo);
      }
      #pragma unroll
      for (int ni = 0; ni < WC; ++ni) {
        int lr = wc * (BN / 2) + ni * 16 + (lane & 15);
        int slot = (kk * 4 + (lane >> 4)) ^ (lr & 7);
        int eo = lr * 64 + slot * 8;
        bh[ni] = *reinterpret_cast<const short8*>(bHi + eo);
        bl[ni] = *reinterpret_cast<const short8*>(bLo + eo);
      }
      #pragma unroll
      for (int mi = 0; mi < 4; ++mi)
        #pragma unroll
        for (int ni = 0; ni < WC; ++ni) {
          acc[mi][ni] = __builtin_amdgcn_mfma_f32_16x16x32_bf16(ah[mi], bh[ni], acc[mi][ni], 0, 0, 0);
          acc[mi][ni] = __builtin_amdgcn_mfma_f32_16x16x32_bf16(ah[mi], bl[ni], acc[mi][ni], 0, 0, 0);
          acc[mi][ni] = __builtin_amdgcn_mfma_f32_16x16x32_bf16(al[mi], bh[ni], acc[mi][ni], 0, 0, 0);
        }
    }
    __syncthreads();
  }

  // C/D layout: col = lane&15, row = (lane>>4)*4 + r
  #pragma unroll
  for (int ni = 0; ni < WC; ++ni) {
    int cc = col0 + wc * (BN / 2) + ni * 16 + (lane & 15);
    float sc = 0.f, tc = 0.f;
    if (EPI == 1) { sc = bn_s[cc]; tc = bn_t[cc]; }
    #pragma unroll
    for (int mi = 0; mi < 4; ++mi) {
      int rbase = row0 + wr * 64 + mi * 16 + (lane >> 4) * 4;
      #pragma unroll
      for (int r = 0; r < 4; ++r) {
        int rr = rbase + r;
        if (rr < M) {
          float v = acc[mi][ni][r];
          if (EPI == 1) {
            v = fmaxf(v * sc + tc, 0.f);
            unsigned short hv = f2bf(v);
            O1[(size_t)rr * N + cc] = hv;
            O2[(size_t)rr * N + cc] = f2bf(v - bf2f(hv));
          } else {
            C[(size_t)rr * N + cc] = v;
            O1[(size_t)rr * N + cc] = f2bf(v);
          }
        }
      }
    }
  }
}

// ---------- agg2: out = A_norm * h2 + b2 (gather bf16 h2, self from fp32 h2) ----------

__global__ __launch_bounds__(256) void agg2_k(
    const int* __restrict__ ptr, const int* __restrict__ ss,
    const float* __restrict__ dinv, const float* __restrict__ h2,
    const unsigned short* __restrict__ h2bf, const float* __restrict__ b2,
    float* __restrict__ out, int n) {
  int w = threadIdx.x >> 6;
  int lane = threadIdx.x & 63;
  int i = blockIdx.x * 4 + w;
  if (i >= n) return;
  int beg = ptr[i], end = ptr[i + 1];
  float di = dinv[i];
  float a = 0.f;
  int e = beg;
  for (; e + 8 <= end; e += 8) {
    int s[8];
    float c[8];
    unsigned short v[8];
    #pragma unroll
    for (int j = 0; j < 8; ++j) s[j] = ss[e + j];
    #pragma unroll
    for (int j = 0; j < 8; ++j) {
      c[j] = dinv[s[j]];
      v[j] = h2bf[(size_t)s[j] * CDIM + lane];
    }
    #pragma unroll
    for (int j = 0; j < 8; ++j) a += c[j] * bf2f(v[j]);
  }
  for (; e < end; ++e) {
    int s = ss[e];
    a += dinv[s] * bf2f(h2bf[(size_t)s * CDIM + lane]);
  }
  a = a * di + h2[(size_t)i * CDIM + lane] * di * di + b2[lane];
  out[(size_t)i * CDIM + lane] = a;
}

extern "C" void kernel_launch(void* const* d_in, const int* in_sizes, int n_in,
                              void* d_out, int out_size, void* d_ws, size_t ws_size,
                              hipStream_t stream) {
  const float* x     = (const float*)d_in[0];
  const int*   ei    = (const int*)d_in[1];
  const float* W1    = (const float*)d_in[2];
  const float* b1    = (const float*)d_in[3];
  const float* gamma = (const float*)d_in[4];
  const float* beta  = (const float*)d_in[5];
  const float* rm    = (const float*)d_in[6];
  const float* rv    = (const float*)d_in[7];
  const float* W2    = (const float*)d_in[8];
  const float* b2    = (const float*)d_in[9];
  float* out = (float*)d_out;

  const int* src = ei;
  const int* dst = ei + NEDGES;

  char* ws = (char*)d_ws;
  auto alloc = [&](size_t bytes) {
    void* p = ws;
    ws += (bytes + 255) & ~(size_t)255;
    return p;
  };
  const int NB = (NNODES + 511) / 512;
  int*   cnt      = (int*)alloc((size_t)NNODES * 4);
  int*   ptr      = (int*)alloc(((size_t)NNODES + 1) * 4);
  int*   cursor   = (int*)alloc((size_t)NNODES * 4);
  float* dinv     = (float*)alloc((size_t)NNODES * 4);
  int*   s_sorted = (int*)alloc((size_t)NEDGES * 4);
  int*   partial  = (int*)alloc((size_t)NB * 4);
  int*   pscan    = (int*)alloc((size_t)NB * 4);
  unsigned short* xbf    = (unsigned short*)alloc((size_t)NNODES * FIN * 2);   // -> houtHi
  unsigned short* xhHi   = (unsigned short*)alloc((size_t)NNODES * FIN * 2);   // -> h2 (fp32, 25.6MB)
  unsigned short* xhLo   = (unsigned short*)alloc((size_t)NNODES * FIN * 2);   // -> h2bf
  unsigned short* houtLo = (unsigned short*)alloc((size_t)NNODES * HDIM * 2);
  unsigned short* w1thi  = (unsigned short*)alloc((size_t)HDIM * FIN * 2);
  unsigned short* w1tlo  = (unsigned short*)alloc((size_t)HDIM * FIN * 2);
  unsigned short* w2thi  = (unsigned short*)alloc((size_t)CDIM * HDIM * 2);
  unsigned short* w2tlo  = (unsigned short*)alloc((size_t)CDIM * HDIM * 2);
  float* bn_s = (float*)alloc(HDIM * 4);
  float* bn_t = (float*)alloc(HDIM * 4);

  unsigned short* houtHi = xbf;                 // alias: xbf dead after agg_x
  float*          h2     = (float*)xhHi;        // alias: xhat dead after GEMM1
  unsigned short* h2bf   = xhLo;                // alias

  // CSR build
  hipMemsetAsync(cnt, 0, (size_t)NNODES * 4, stream);
  hist_k<<<(NEDGES + 255) / 256, 256, 0, stream>>>(dst, cnt, NEDGES);
  dinv_k<<<(NNODES + 255) / 256, 256, 0, stream>>>(cnt, dinv, NNODES);
  partial_k<<<NB, 256, 0, stream>>>(cnt, partial, NNODES);
  scanpart_k<<<1, 256, 0, stream>>>(partial, pscan, NB);
  apply_k<<<NB, 256, 0, stream>>>(cnt, pscan, ptr, cursor, NNODES);
  scatter_k<<<(NEDGES + 255) / 256, 256, 0, stream>>>(src, dst, cursor, s_sorted, NEDGES);

  // prep
  xbf_k<<<12800, 256, 0, stream>>>(x, xbf, NNODES * FIN / 4);
  bn_prep_k<<<1, HDIM, 0, stream>>>(b1, gamma, beta, rm, rv, bn_s, bn_t);
  split_wt_k<<<HDIM, 256, 0, stream>>>(W1, w1thi, w1tlo, FIN, HDIM);
  split_wt_k<<<CDIM, 256, 0, stream>>>(W2, w2thi, w2tlo, HDIM, CDIM);

  // layer 1 reordered: xhat = A_norm*x, then hout = relu(BN(xhat@W1+b1))
  agg_x_k<<<(NNODES + 3) / 4, 256, 0, stream>>>(ptr, s_sorted, dinv, xbf, x, xhHi, xhLo, NNODES);
  gemm_split_k<128, 1><<<dim3((NNODES + 127) / 128, HDIM / 128), 256, 0, stream>>>(
      xhHi, xhLo, w1thi, w1tlo, nullptr, houtHi, houtLo, bn_s, bn_t, NNODES, HDIM, FIN);

  // layer 2: h2 = hout@W2, then out = A_norm*h2 + b2
  gemm_split_k<64, 2><<<dim3((NNODES + 127) / 128, 1), 256, 0, stream>>>(
      houtHi, houtLo, w2thi, w2tlo, h2, h2bf, nullptr, nullptr, nullptr, NNODES, CDIM, HDIM);
  agg2_k<<<(NNODES + 3) / 4, 256, 0, stream>>>(ptr, s_sorted, dinv, h2, h2bf, b2, out, NNODES);
}

// Round 5
// 515.277 us; speedup vs baseline: 13.9724x; 1.0849x over previous
//
#include <hip/hip_runtime.h>

#define NNODES 100000
#define NEDGES 1600000
#define FIN 256
#define HDIM 256
#define CDIM 64
#define BN_EPS 1e-5f

typedef __attribute__((ext_vector_type(8))) short short8;
typedef __attribute__((ext_vector_type(4))) float f32x4;

static __device__ __forceinline__ unsigned short f2bf(float f) {
  unsigned u = __float_as_uint(f);
  u += 0x7FFF + ((u >> 16) & 1);
  return (unsigned short)(u >> 16);
}
static __device__ __forceinline__ float bf2f(unsigned short h) {
  return __uint_as_float(((unsigned)h) << 16);
}

// ---------- degree / CSR build ----------

__global__ void hist_k(const int* __restrict__ dst, int* __restrict__ cnt, int e) {
  int i = blockIdx.x * blockDim.x + threadIdx.x;
  if (i < e) atomicAdd(&cnt[dst[i]], 1);
}

__global__ __launch_bounds__(256) void partial_k(const int* __restrict__ cnt,
                                                 int* __restrict__ partial, int n) {
  int base = blockIdx.x * 512;
  int s = 0;
  for (int i = threadIdx.x; i < 512; i += 256) {
    int g = base + i;
    if (g < n) s += cnt[g];
  }
  #pragma unroll
  for (int off = 32; off > 0; off >>= 1) s += __shfl_down(s, off, 64);
  __shared__ int red[4];
  if ((threadIdx.x & 63) == 0) red[threadIdx.x >> 6] = s;
  __syncthreads();
  if (threadIdx.x == 0) partial[blockIdx.x] = red[0] + red[1] + red[2] + red[3];
}

__global__ __launch_bounds__(256) void scanpart_k(const int* __restrict__ partial,
                                                  int* __restrict__ pscan, int nb) {
  __shared__ int sm[256];
  int t = threadIdx.x;
  int v = (t < nb) ? partial[t] : 0;
  sm[t] = v;
  __syncthreads();
  for (int off = 1; off < 256; off <<= 1) {
    int x = (t >= off) ? sm[t - off] : 0;
    __syncthreads();
    sm[t] += x;
    __syncthreads();
  }
  if (t < nb) pscan[t] = sm[t] - v;
}

// scan-apply + dinv fused
__global__ __launch_bounds__(256) void apply_k(const int* __restrict__ cnt,
                                               const int* __restrict__ pscan,
                                               int* __restrict__ ptr,
                                               int* __restrict__ cursor,
                                               float* __restrict__ dinv, int n) {
  __shared__ int wsum[4];
  int tid = threadIdx.x, lane = tid & 63, w = tid >> 6;
  int base = blockIdx.x * 512;
  int running = pscan[blockIdx.x];
  for (int rp = 0; rp < 2; ++rp) {
    int i = base + rp * 256 + tid;
    int v = (i < n) ? cnt[i] : 0;
    int x = v;
    #pragma unroll
    for (int off = 1; off < 64; off <<= 1) {
      int t = __shfl_up(x, off, 64);
      if (lane >= off) x += t;
    }
    if (lane == 63) wsum[w] = x;
    __syncthreads();
    int wb = 0;
    for (int j = 0; j < w; ++j) wb += wsum[j];
    int excl = running + wb + x - v;
    if (i < n) {
      ptr[i] = excl;
      cursor[i] = excl;
      dinv[i] = rsqrtf((float)v + 1.0f);
    }
    int tot = wsum[0] + wsum[1] + wsum[2] + wsum[3];
    __syncthreads();
    running += tot;
  }
  if (blockIdx.x == 0 && tid == 0) ptr[n] = NEDGES;
}

__global__ void scatter_k(const int* __restrict__ src, const int* __restrict__ dst,
                          int* __restrict__ cursor, int* __restrict__ s_sorted, int e) {
  int i = blockIdx.x * blockDim.x + threadIdx.x;
  if (i < e) {
    int d = dst[i];
    int pos = atomicAdd(&cursor[d], 1);
    s_sorted[pos] = src[i];
  }
}

// ---------- conversions / prep ----------

__global__ void xbf_k(const float* __restrict__ x, unsigned short* __restrict__ xbf, int n4) {
  int i = blockIdx.x * blockDim.x + threadIdx.x;
  int stride = gridDim.x * blockDim.x;
  for (; i < n4; i += stride) {
    float4 v = reinterpret_cast<const float4*>(x)[i];
    reinterpret_cast<ushort4*>(xbf)[i] =
        make_ushort4(f2bf(v.x), f2bf(v.y), f2bf(v.z), f2bf(v.w));
  }
}

// W[K][N] fp32 -> Wt[N][K] bf16 hi/lo (tiny)
__global__ void split_wt_k(const float* __restrict__ W, unsigned short* __restrict__ hi,
                           unsigned short* __restrict__ lo, int K, int N) {
  int n = blockIdx.x;
  for (int k = threadIdx.x; k < K; k += blockDim.x) {
    float v = W[(size_t)k * N + n];
    unsigned short h = f2bf(v);
    hi[(size_t)n * K + k] = h;
    lo[(size_t)n * K + k] = f2bf(v - bf2f(h));
  }
}

__global__ void bn_prep_k(const float* __restrict__ b1, const float* __restrict__ gamma,
                          const float* __restrict__ beta, const float* __restrict__ rm,
                          const float* __restrict__ rv, float* __restrict__ bn_s,
                          float* __restrict__ bn_t) {
  int f = threadIdx.x;
  float s = gamma[f] * rsqrtf(rv[f] + BN_EPS);
  bn_s[f] = s;
  bn_t[f] = (b1[f] - rm[f]) * s + beta[f];
}

// ---------- agg_x: xhat = A_norm * x (all-bf16 gather incl. self), emits bf16 hi only ----------

__global__ __launch_bounds__(256) void agg_x_k(
    const int* __restrict__ ptr, const int* __restrict__ ss,
    const float* __restrict__ dinv, const unsigned short* __restrict__ xbf,
    unsigned short* __restrict__ xhHi, int n) {
  int w = threadIdx.x >> 6;
  int lane = threadIdx.x & 63;
  int i = blockIdx.x * 4 + w;
  if (i >= n) return;
  int beg = ptr[i], end = ptr[i + 1];
  float di = dinv[i];
  int f0 = lane * 4;
  float ax = 0.f, ay = 0.f, az = 0.f, aw = 0.f;
  int e = beg;
  for (; e + 8 <= end; e += 8) {
    int s[8];
    float c[8];
    ushort4 v[8];
    #pragma unroll
    for (int j = 0; j < 8; ++j) s[j] = ss[e + j];
    #pragma unroll
    for (int j = 0; j < 8; ++j) {
      c[j] = dinv[s[j]];
      v[j] = *reinterpret_cast<const ushort4*>(xbf + (size_t)s[j] * FIN + f0);
    }
    #pragma unroll
    for (int j = 0; j < 8; ++j) {
      ax += c[j] * bf2f(v[j].x);
      ay += c[j] * bf2f(v[j].y);
      az += c[j] * bf2f(v[j].z);
      aw += c[j] * bf2f(v[j].w);
    }
  }
  for (; e < end; ++e) {
    int s = ss[e];
    float c = dinv[s];
    ushort4 v = *reinterpret_cast<const ushort4*>(xbf + (size_t)s * FIN + f0);
    ax += c * bf2f(v.x); ay += c * bf2f(v.y); az += c * bf2f(v.z); aw += c * bf2f(v.w);
  }
  ushort4 vs = *reinterpret_cast<const ushort4*>(xbf + (size_t)i * FIN + f0);
  float di2 = di * di;
  ax = ax * di + bf2f(vs.x) * di2;
  ay = ay * di + bf2f(vs.y) * di2;
  az = az * di + bf2f(vs.z) * di2;
  aw = aw * di + bf2f(vs.w) * di2;
  *reinterpret_cast<ushort4*>(xhHi + (size_t)i * FIN + f0) =
      make_ushort4(f2bf(ax), f2bf(ay), f2bf(az), f2bf(aw));
}

// ---------- split-bf16 MFMA GEMM: C = A*Bt^T. BM=128, BK=64. ----------
// ALO: 3-term (AhiBhi+AhiBlo+AloBhi); else 2-term (AhiBhi+AhiBlo).
// EPI=1: O1 = bf16(relu(v*bn_s+bn_t)) hi, O2 = lo  (GEMM1)
// EPI=2: C fp32, O1 = bf16(v)                       (GEMM2)

template <int BN, int EPI, bool ALO>
__global__ __launch_bounds__(256) void gemm_split_k(
    const unsigned short* __restrict__ Ahi, const unsigned short* __restrict__ Alo,
    const unsigned short* __restrict__ Bhi, const unsigned short* __restrict__ Blo,
    float* __restrict__ C, unsigned short* __restrict__ O1,
    unsigned short* __restrict__ O2, const float* __restrict__ bn_s,
    const float* __restrict__ bn_t, int M, int N, int K) {
  constexpr int WC = BN / 32;
  constexpr int ASZ = (ALO ? 2 : 1) * 128 * 64;
  __shared__ unsigned short smem[ASZ + 2 * BN * 64];
  unsigned short* aHi = smem;
  unsigned short* aLo = smem + 128 * 64;  // only if ALO
  unsigned short* bHi = smem + ASZ;
  unsigned short* bLo = bHi + BN * 64;

  const int tid = threadIdx.x;
  const int w = tid >> 6;
  const int lane = tid & 63;
  const int wr = w >> 1, wc = w & 1;
  const int row0 = blockIdx.x * 128;
  const int col0 = blockIdx.y * BN;

  f32x4 acc[4][WC];
  #pragma unroll
  for (int mi = 0; mi < 4; ++mi)
    #pragma unroll
    for (int ni = 0; ni < WC; ++ni) {
      f32x4 z = {0.f, 0.f, 0.f, 0.f};
      acc[mi][ni] = z;
    }

  auto stage = [&](const unsigned short* G, unsigned short* Ld, int rows, int gr0,
                   int maxRow, int k0) {
    for (int i = 0; i < rows / 32; ++i) {
      int chunk = i * 256 + tid;
      int r = chunk >> 3;
      int c = chunk & 7;
      int cs = c ^ (r & 7);
      int gr = gr0 + r;
      if (gr > maxRow) gr = maxRow;
      const unsigned short* gp = G + (size_t)gr * K + k0 + cs * 8;
      unsigned short* lp = Ld + (i * 256 + w * 64) * 8;
      __builtin_amdgcn_global_load_lds((const __attribute__((address_space(1))) void*)gp,
                                       (__attribute__((address_space(3))) void*)lp, 16, 0, 0);
    }
  };

  for (int k0 = 0; k0 < K; k0 += 64) {
    stage(Ahi, aHi, 128, row0, M - 1, k0);
    if constexpr (ALO) stage(Alo, aLo, 128, row0, M - 1, k0);
    stage(Bhi, bHi, BN, col0, N - 1, k0);
    stage(Blo, bLo, BN, col0, N - 1, k0);
    __syncthreads();
    #pragma unroll
    for (int kk = 0; kk < 2; ++kk) {
      short8 ah[4], al[4], bh[WC], bl[WC];
      #pragma unroll
      for (int mi = 0; mi < 4; ++mi) {
        int lr = wr * 64 + mi * 16 + (lane & 15);
        int slot = (kk * 4 + (lane >> 4)) ^ (lr & 7);
        int eo = lr * 64 + slot * 8;
        ah[mi] = *reinterpret_cast<const short8*>(aHi + eo);
        if constexpr (ALO) al[mi] = *reinterpret_cast<const short8*>(aLo + eo);
      }
      #pragma unroll
      for (int ni = 0; ni < WC; ++ni) {
        int lr = wc * (BN / 2) + ni * 16 + (lane & 15);
        int slot = (kk * 4 + (lane >> 4)) ^ (lr & 7);
        int eo = lr * 64 + slot * 8;
        bh[ni] = *reinterpret_cast<const short8*>(bHi + eo);
        bl[ni] = *reinterpret_cast<const short8*>(bLo + eo);
      }
      #pragma unroll
      for (int mi = 0; mi < 4; ++mi)
        #pragma unroll
        for (int ni = 0; ni < WC; ++ni) {
          acc[mi][ni] = __builtin_amdgcn_mfma_f32_16x16x32_bf16(ah[mi], bh[ni], acc[mi][ni], 0, 0, 0);
          acc[mi][ni] = __builtin_amdgcn_mfma_f32_16x16x32_bf16(ah[mi], bl[ni], acc[mi][ni], 0, 0, 0);
          if constexpr (ALO)
            acc[mi][ni] = __builtin_amdgcn_mfma_f32_16x16x32_bf16(al[mi], bh[ni], acc[mi][ni], 0, 0, 0);
        }
    }
    __syncthreads();
  }

  // C/D layout: col = lane&15, row = (lane>>4)*4 + r
  #pragma unroll
  for (int ni = 0; ni < WC; ++ni) {
    int cc = col0 + wc * (BN / 2) + ni * 16 + (lane & 15);
    float sc = 0.f, tc = 0.f;
    if (EPI == 1) { sc = bn_s[cc]; tc = bn_t[cc]; }
    #pragma unroll
    for (int mi = 0; mi < 4; ++mi) {
      int rbase = row0 + wr * 64 + mi * 16 + (lane >> 4) * 4;
      #pragma unroll
      for (int r = 0; r < 4; ++r) {
        int rr = rbase + r;
        if (rr < M) {
          float v = acc[mi][ni][r];
          if (EPI == 1) {
            v = fmaxf(v * sc + tc, 0.f);
            unsigned short hv = f2bf(v);
            O1[(size_t)rr * N + cc] = hv;
            O2[(size_t)rr * N + cc] = f2bf(v - bf2f(hv));
          } else {
            C[(size_t)rr * N + cc] = v;
            O1[(size_t)rr * N + cc] = f2bf(v);
          }
        }
      }
    }
  }
}

// ---------- agg2: out = A_norm*h2 + b2. Half-wave per edge, ushort2 per lane. ----------

__global__ __launch_bounds__(256) void agg2_k(
    const int* __restrict__ ptr, const int* __restrict__ ss,
    const float* __restrict__ dinv, const float* __restrict__ h2,
    const unsigned short* __restrict__ h2bf, const float* __restrict__ b2,
    float* __restrict__ out, int n) {
  int w = threadIdx.x >> 6;
  int lane = threadIdx.x & 63;
  int i = blockIdx.x * 4 + w;
  if (i >= n) return;
  int sub = lane >> 5;       // 0: even edges, 1: odd edges
  int f2 = (lane & 31) * 2;  // feature pair
  int beg = ptr[i], end = ptr[i + 1];
  float di = dinv[i];
  float a0 = 0.f, a1 = 0.f;
  int e = beg;
  for (; e + 8 <= end; e += 8) {
    int s0 = ss[e + sub], s1 = ss[e + 2 + sub], s2 = ss[e + 4 + sub], s3 = ss[e + 6 + sub];
    float c0 = dinv[s0], c1 = dinv[s1], c2 = dinv[s2], c3 = dinv[s3];
    ushort2 v0 = *reinterpret_cast<const ushort2*>(h2bf + (size_t)s0 * CDIM + f2);
    ushort2 v1 = *reinterpret_cast<const ushort2*>(h2bf + (size_t)s1 * CDIM + f2);
    ushort2 v2 = *reinterpret_cast<const ushort2*>(h2bf + (size_t)s2 * CDIM + f2);
    ushort2 v3 = *reinterpret_cast<const ushort2*>(h2bf + (size_t)s3 * CDIM + f2);
    a0 += c0 * bf2f(v0.x) + c1 * bf2f(v1.x) + c2 * bf2f(v2.x) + c3 * bf2f(v3.x);
    a1 += c0 * bf2f(v0.y) + c1 * bf2f(v1.y) + c2 * bf2f(v2.y) + c3 * bf2f(v3.y);
  }
  for (; e < end; e += 2) {
    int idx = e + sub;
    if (idx < end) {
      int s = ss[idx];
      float c = dinv[s];
      ushort2 v = *reinterpret_cast<const ushort2*>(h2bf + (size_t)s * CDIM + f2);
      a0 += c * bf2f(v.x);
      a1 += c * bf2f(v.y);
    }
  }
  a0 += __shfl_xor(a0, 32);
  a1 += __shfl_xor(a1, 32);
  if (sub == 0) {
    float2 self = *reinterpret_cast<const float2*>(h2 + (size_t)i * CDIM + f2);
    float2 vb2 = *reinterpret_cast<const float2*>(b2 + f2);
    float di2 = di * di;
    float2 o;
    o.x = a0 * di + self.x * di2 + vb2.x;
    o.y = a1 * di + self.y * di2 + vb2.y;
    *reinterpret_cast<float2*>(out + (size_t)i * CDIM + f2) = o;
  }
}

extern "C" void kernel_launch(void* const* d_in, const int* in_sizes, int n_in,
                              void* d_out, int out_size, void* d_ws, size_t ws_size,
                              hipStream_t stream) {
  const float* x     = (const float*)d_in[0];
  const int*   ei    = (const int*)d_in[1];
  const float* W1    = (const float*)d_in[2];
  const float* b1    = (const float*)d_in[3];
  const float* gamma = (const float*)d_in[4];
  const float* beta  = (const float*)d_in[5];
  const float* rm    = (const float*)d_in[6];
  const float* rv    = (const float*)d_in[7];
  const float* W2    = (const float*)d_in[8];
  const float* b2    = (const float*)d_in[9];
  float* out = (float*)d_out;

  const int* src = ei;
  const int* dst = ei + NEDGES;

  char* ws = (char*)d_ws;
  auto alloc = [&](size_t bytes) {
    void* p = ws;
    ws += (bytes + 255) & ~(size_t)255;
    return p;
  };
  const int NB = (NNODES + 511) / 512;
  int*   cnt      = (int*)alloc((size_t)NNODES * 4);
  int*   ptr      = (int*)alloc(((size_t)NNODES + 1) * 4);
  int*   cursor   = (int*)alloc((size_t)NNODES * 4);
  float* dinv     = (float*)alloc((size_t)NNODES * 4);
  int*   s_sorted = (int*)alloc((size_t)NEDGES * 4);
  int*   partial  = (int*)alloc((size_t)NB * 4);
  int*   pscan    = (int*)alloc((size_t)NB * 4);
  unsigned short* xbf    = (unsigned short*)alloc((size_t)NNODES * FIN * 2);  // -> houtHi
  unsigned short* xhHi   = (unsigned short*)alloc((size_t)NNODES * FIN * 2);  // -> h2 (fp32)
  unsigned short* houtLo = (unsigned short*)alloc((size_t)NNODES * HDIM * 2);
  unsigned short* h2bf   = (unsigned short*)alloc((size_t)NNODES * CDIM * 2);
  unsigned short* w1thi  = (unsigned short*)alloc((size_t)HDIM * FIN * 2);
  unsigned short* w1tlo  = (unsigned short*)alloc((size_t)HDIM * FIN * 2);
  unsigned short* w2thi  = (unsigned short*)alloc((size_t)CDIM * HDIM * 2);
  unsigned short* w2tlo  = (unsigned short*)alloc((size_t)CDIM * HDIM * 2);
  float* bn_s = (float*)alloc(HDIM * 4);
  float* bn_t = (float*)alloc(HDIM * 4);

  unsigned short* houtHi = xbf;           // alias: xbf dead after agg_x
  float*          h2     = (float*)xhHi;  // alias: xhat dead after GEMM1 (25.6MB < 51.2MB)

  // CSR build (+ dinv fused into apply)
  hipMemsetAsync(cnt, 0, (size_t)NNODES * 4, stream);
  hist_k<<<(NEDGES + 255) / 256, 256, 0, stream>>>(dst, cnt, NEDGES);
  partial_k<<<NB, 256, 0, stream>>>(cnt, partial, NNODES);
  scanpart_k<<<1, 256, 0, stream>>>(partial, pscan, NB);
  apply_k<<<NB, 256, 0, stream>>>(cnt, pscan, ptr, cursor, dinv, NNODES);
  scatter_k<<<(NEDGES + 255) / 256, 256, 0, stream>>>(src, dst, cursor, s_sorted, NEDGES);

  // prep
  xbf_k<<<12800, 256, 0, stream>>>(x, xbf, NNODES * FIN / 4);
  bn_prep_k<<<1, HDIM, 0, stream>>>(b1, gamma, beta, rm, rv, bn_s, bn_t);
  split_wt_k<<<HDIM, 256, 0, stream>>>(W1, w1thi, w1tlo, FIN, HDIM);
  split_wt_k<<<CDIM, 256, 0, stream>>>(W2, w2thi, w2tlo, HDIM, CDIM);

  // layer 1 reordered: xhat = A_norm*x (bf16), hout = relu(BN(xhat@W1+b1)) in GEMM epilogue
  agg_x_k<<<(NNODES + 3) / 4, 256, 0, stream>>>(ptr, s_sorted, dinv, xbf, xhHi, NNODES);
  gemm_split_k<128, 1, false><<<dim3((NNODES + 127) / 128, HDIM / 128), 256, 0, stream>>>(
      xhHi, nullptr, w1thi, w1tlo, nullptr, houtHi, houtLo, bn_s, bn_t, NNODES, HDIM, FIN);

  // layer 2: h2 = hout@W2 (3-term), out = A_norm*h2 + b2
  gemm_split_k<64, 2, true><<<dim3((NNODES + 127) / 128, 1), 256, 0, stream>>>(
      houtHi, houtLo, w2thi, w2tlo, h2, h2bf, nullptr, nullptr, nullptr, NNODES, CDIM, HDIM);
  agg2_k<<<(NNODES + 3) / 4, 256, 0, stream>>>(ptr, s_sorted, dinv, h2, h2bf, b2, out, NNODES);
}

// Round 6
// 506.900 us; speedup vs baseline: 14.2034x; 1.0165x over previous
//
#include <hip/hip_runtime.h>

#define NNODES 100000
#define NEDGES 1600000
#define FIN 256
#define HDIM 256
#define CDIM 64
#define BN_EPS 1e-5f
#define NSUB 8

typedef __attribute__((ext_vector_type(8))) short short8;
typedef __attribute__((ext_vector_type(8))) unsigned short ushort8_t;
typedef __attribute__((ext_vector_type(4))) float f32x4;

static __device__ __forceinline__ unsigned short f2bf(float f) {
  unsigned u = __float_as_uint(f);
  u += 0x7FFF + ((u >> 16) & 1);
  return (unsigned short)(u >> 16);
}
static __device__ __forceinline__ float bf2f(unsigned short h) {
  return __uint_as_float(((unsigned)h) << 16);
}

// ---------- degree / CSR build (8-way sub-binned to cut atomic RMW chains) ----------

__global__ void hist_k(const int* __restrict__ dst, int* __restrict__ cnt_sub, int e) {
  int i = blockIdx.x * 256 + threadIdx.x;
  int sub = blockIdx.x & (NSUB - 1);
  if (i < e) atomicAdd(&cnt_sub[sub * NNODES + dst[i]], 1);
}

__global__ void reduce_k(const int* __restrict__ cnt_sub, int* __restrict__ cnt, int n) {
  int i = blockIdx.x * blockDim.x + threadIdx.x;
  if (i < n) {
    int t = 0;
    #pragma unroll
    for (int s = 0; s < NSUB; ++s) t += cnt_sub[s * NNODES + i];
    cnt[i] = t;
  }
}

__global__ __launch_bounds__(256) void partial_k(const int* __restrict__ cnt,
                                                 int* __restrict__ partial, int n) {
  int base = blockIdx.x * 512;
  int s = 0;
  for (int i = threadIdx.x; i < 512; i += 256) {
    int g = base + i;
    if (g < n) s += cnt[g];
  }
  #pragma unroll
  for (int off = 32; off > 0; off >>= 1) s += __shfl_down(s, off, 64);
  __shared__ int red[4];
  if ((threadIdx.x & 63) == 0) red[threadIdx.x >> 6] = s;
  __syncthreads();
  if (threadIdx.x == 0) partial[blockIdx.x] = red[0] + red[1] + red[2] + red[3];
}

__global__ __launch_bounds__(256) void scanpart_k(const int* __restrict__ partial,
                                                  int* __restrict__ pscan, int nb) {
  __shared__ int sm[256];
  int t = threadIdx.x;
  int v = (t < nb) ? partial[t] : 0;
  sm[t] = v;
  __syncthreads();
  for (int off = 1; off < 256; off <<= 1) {
    int x = (t >= off) ? sm[t - off] : 0;
    __syncthreads();
    sm[t] += x;
    __syncthreads();
  }
  if (t < nb) pscan[t] = sm[t] - v;
}

// scan-apply + dinv fused
__global__ __launch_bounds__(256) void apply_k(const int* __restrict__ cnt,
                                               const int* __restrict__ pscan,
                                               int* __restrict__ ptr,
                                               float* __restrict__ dinv, int n) {
  __shared__ int wsum[4];
  int tid = threadIdx.x, lane = tid & 63, w = tid >> 6;
  int base = blockIdx.x * 512;
  int running = pscan[blockIdx.x];
  for (int rp = 0; rp < 2; ++rp) {
    int i = base + rp * 256 + tid;
    int v = (i < n) ? cnt[i] : 0;
    int x = v;
    #pragma unroll
    for (int off = 1; off < 64; off <<= 1) {
      int t = __shfl_up(x, off, 64);
      if (lane >= off) x += t;
    }
    if (lane == 63) wsum[w] = x;
    __syncthreads();
    int wb = 0;
    for (int j = 0; j < w; ++j) wb += wsum[j];
    int excl = running + wb + x - v;
    if (i < n) {
      ptr[i] = excl;
      dinv[i] = rsqrtf((float)v + 1.0f);
    }
    int tot = wsum[0] + wsum[1] + wsum[2] + wsum[3];
    __syncthreads();
    running += tot;
  }
  if (blockIdx.x == 0 && tid == 0) ptr[n] = NEDGES;
}

// cursor_sub[s][i] = ptr[i] + sum_{t<s} cnt_sub[t][i]
__global__ void suboff_k(const int* __restrict__ cnt_sub, const int* __restrict__ ptr,
                         int* __restrict__ cursor_sub, int n) {
  int i = blockIdx.x * blockDim.x + threadIdx.x;
  if (i < n) {
    int base = ptr[i];
    #pragma unroll
    for (int s = 0; s < NSUB; ++s) {
      cursor_sub[s * NNODES + i] = base;
      base += cnt_sub[s * NNODES + i];
    }
  }
}

__global__ void scatter_k(const int* __restrict__ src, const int* __restrict__ dst,
                          int* __restrict__ cursor_sub, int* __restrict__ s_sorted, int e) {
  int i = blockIdx.x * 256 + threadIdx.x;
  int sub = blockIdx.x & (NSUB - 1);
  if (i < e) {
    int d = dst[i];
    int pos = atomicAdd(&cursor_sub[sub * NNODES + d], 1);
    s_sorted[pos] = src[i];
  }
}

// ---------- conversions / prep ----------

__global__ void xbf_k(const float* __restrict__ x, unsigned short* __restrict__ xbf, int n4) {
  int i = blockIdx.x * blockDim.x + threadIdx.x;
  int stride = gridDim.x * blockDim.x;
  for (; i < n4; i += stride) {
    float4 v = reinterpret_cast<const float4*>(x)[i];
    reinterpret_cast<ushort4*>(xbf)[i] =
        make_ushort4(f2bf(v.x), f2bf(v.y), f2bf(v.z), f2bf(v.w));
  }
}

// W[K][N] fp32 -> Wt[N][K] bf16 hi/lo (tiny)
__global__ void split_wt_k(const float* __restrict__ W, unsigned short* __restrict__ hi,
                           unsigned short* __restrict__ lo, int K, int N) {
  int n = blockIdx.x;
  for (int k = threadIdx.x; k < K; k += blockDim.x) {
    float v = W[(size_t)k * N + n];
    unsigned short h = f2bf(v);
    hi[(size_t)n * K + k] = h;
    lo[(size_t)n * K + k] = f2bf(v - bf2f(h));
  }
}

__global__ void bn_prep_k(const float* __restrict__ b1, const float* __restrict__ gamma,
                          const float* __restrict__ beta, const float* __restrict__ rm,
                          const float* __restrict__ rv, float* __restrict__ bn_s,
                          float* __restrict__ bn_t) {
  int f = threadIdx.x;
  float s = gamma[f] * rsqrtf(rv[f] + BN_EPS);
  bn_s[f] = s;
  bn_t[f] = (b1[f] - rm[f]) * s + beta[f];
}

// ---------- agg_x: xhat = A_norm * x. Half-wave per edge, ushort8 (16B) per lane. ----------

__global__ __launch_bounds__(256) void agg_x_k(
    const int* __restrict__ ptr, const int* __restrict__ ss,
    const float* __restrict__ dinv, const unsigned short* __restrict__ xbf,
    unsigned short* __restrict__ xhHi, int n) {
  int w = threadIdx.x >> 6;
  int lane = threadIdx.x & 63;
  int i = blockIdx.x * 4 + w;
  if (i >= n) return;
  int sub = lane >> 5;       // 0: even edges, 1: odd edges
  int f8 = (lane & 31) * 8;  // 8 features per lane
  int beg = ptr[i], end = ptr[i + 1];
  float di = dinv[i];
  float a[8] = {};
  int e = beg;
  for (; e + 8 <= end; e += 8) {
    int s0 = ss[e + sub], s1 = ss[e + 2 + sub], s2 = ss[e + 4 + sub], s3 = ss[e + 6 + sub];
    float c0 = dinv[s0], c1 = dinv[s1], c2 = dinv[s2], c3 = dinv[s3];
    ushort8_t v0 = *reinterpret_cast<const ushort8_t*>(xbf + (size_t)s0 * FIN + f8);
    ushort8_t v1 = *reinterpret_cast<const ushort8_t*>(xbf + (size_t)s1 * FIN + f8);
    ushort8_t v2 = *reinterpret_cast<const ushort8_t*>(xbf + (size_t)s2 * FIN + f8);
    ushort8_t v3 = *reinterpret_cast<const ushort8_t*>(xbf + (size_t)s3 * FIN + f8);
    #pragma unroll
    for (int k = 0; k < 8; ++k)
      a[k] += c0 * bf2f(v0[k]) + c1 * bf2f(v1[k]) + c2 * bf2f(v2[k]) + c3 * bf2f(v3[k]);
  }
  for (; e < end; e += 2) {
    int idx = e + sub;
    if (idx < end) {
      int s = ss[idx];
      float c = dinv[s];
      ushort8_t v = *reinterpret_cast<const ushort8_t*>(xbf + (size_t)s * FIN + f8);
      #pragma unroll
      for (int k = 0; k < 8; ++k) a[k] += c * bf2f(v[k]);
    }
  }
  #pragma unroll
  for (int k = 0; k < 8; ++k) a[k] += __shfl_xor(a[k], 32);
  if (sub == 0) {
    ushort8_t vs = *reinterpret_cast<const ushort8_t*>(xbf + (size_t)i * FIN + f8);
    float di2 = di * di;
    ushort8_t o;
    #pragma unroll
    for (int k = 0; k < 8; ++k) o[k] = f2bf(a[k] * di + bf2f(vs[k]) * di2);
    *reinterpret_cast<ushort8_t*>(xhHi + (size_t)i * FIN + f8) = o;
  }
}

// ---------- split-bf16 MFMA GEMM: C = A*Bt^T. BM=128, BK=64. ----------
// ALO: 3-term (AhiBhi+AhiBlo+AloBhi); else 2-term (AhiBhi+AhiBlo).
// EPI=1: O1 = bf16(relu(v*bn_s+bn_t)) hi, O2 = lo  (GEMM1)
// EPI=2: C fp32, O1 = bf16(v)                       (GEMM2)

template <int BN, int EPI, bool ALO>
__global__ __launch_bounds__(256) void gemm_split_k(
    const unsigned short* __restrict__ Ahi, const unsigned short* __restrict__ Alo,
    const unsigned short* __restrict__ Bhi, const unsigned short* __restrict__ Blo,
    float* __restrict__ C, unsigned short* __restrict__ O1,
    unsigned short* __restrict__ O2, const float* __restrict__ bn_s,
    const float* __restrict__ bn_t, int M, int N, int K) {
  constexpr int WC = BN / 32;
  constexpr int ASZ = (ALO ? 2 : 1) * 128 * 64;
  __shared__ unsigned short smem[ASZ + 2 * BN * 64];
  unsigned short* aHi = smem;
  unsigned short* aLo = smem + 128 * 64;  // only if ALO
  unsigned short* bHi = smem + ASZ;
  unsigned short* bLo = bHi + BN * 64;

  const int tid = threadIdx.x;
  const int w = tid >> 6;
  const int lane = tid & 63;
  const int wr = w >> 1, wc = w & 1;
  const int row0 = blockIdx.x * 128;
  const int col0 = blockIdx.y * BN;

  f32x4 acc[4][WC];
  #pragma unroll
  for (int mi = 0; mi < 4; ++mi)
    #pragma unroll
    for (int ni = 0; ni < WC; ++ni) {
      f32x4 z = {0.f, 0.f, 0.f, 0.f};
      acc[mi][ni] = z;
    }

  auto stage = [&](const unsigned short* G, unsigned short* Ld, int rows, int gr0,
                   int maxRow, int k0) {
    for (int i = 0; i < rows / 32; ++i) {
      int chunk = i * 256 + tid;
      int r = chunk >> 3;
      int c = chunk & 7;
      int cs = c ^ (r & 7);
      int gr = gr0 + r;
      if (gr > maxRow) gr = maxRow;
      const unsigned short* gp = G + (size_t)gr * K + k0 + cs * 8;
      unsigned short* lp = Ld + (i * 256 + w * 64) * 8;
      __builtin_amdgcn_global_load_lds((const __attribute__((address_space(1))) void*)gp,
                                       (__attribute__((address_space(3))) void*)lp, 16, 0, 0);
    }
  };

  for (int k0 = 0; k0 < K; k0 += 64) {
    stage(Ahi, aHi, 128, row0, M - 1, k0);
    if constexpr (ALO) stage(Alo, aLo, 128, row0, M - 1, k0);
    stage(Bhi, bHi, BN, col0, N - 1, k0);
    stage(Blo, bLo, BN, col0, N - 1, k0);
    __syncthreads();
    #pragma unroll
    for (int kk = 0; kk < 2; ++kk) {
      short8 ah[4], al[4], bh[WC], bl[WC];
      #pragma unroll
      for (int mi = 0; mi < 4; ++mi) {
        int lr = wr * 64 + mi * 16 + (lane & 15);
        int slot = (kk * 4 + (lane >> 4)) ^ (lr & 7);
        int eo = lr * 64 + slot * 8;
        ah[mi] = *reinterpret_cast<const short8*>(aHi + eo);
        if constexpr (ALO) al[mi] = *reinterpret_cast<const short8*>(aLo + eo);
      }
      #pragma unroll
      for (int ni = 0; ni < WC; ++ni) {
        int lr = wc * (BN / 2) + ni * 16 + (lane & 15);
        int slot = (kk * 4 + (lane >> 4)) ^ (lr & 7);
        int eo = lr * 64 + slot * 8;
        bh[ni] = *reinterpret_cast<const short8*>(bHi + eo);
        bl[ni] = *reinterpret_cast<const short8*>(bLo + eo);
      }
      #pragma unroll
      for (int mi = 0; mi < 4; ++mi)
        #pragma unroll
        for (int ni = 0; ni < WC; ++ni) {
          acc[mi][ni] = __builtin_amdgcn_mfma_f32_16x16x32_bf16(ah[mi], bh[ni], acc[mi][ni], 0, 0, 0);
          acc[mi][ni] = __builtin_amdgcn_mfma_f32_16x16x32_bf16(ah[mi], bl[ni], acc[mi][ni], 0, 0, 0);
          if constexpr (ALO)
            acc[mi][ni] = __builtin_amdgcn_mfma_f32_16x16x32_bf16(al[mi], bh[ni], acc[mi][ni], 0, 0, 0);
        }
    }
    __syncthreads();
  }

  // C/D layout: col = lane&15, row = (lane>>4)*4 + r
  #pragma unroll
  for (int ni = 0; ni < WC; ++ni) {
    int cc = col0 + wc * (BN / 2) + ni * 16 + (lane & 15);
    float sc = 0.f, tc = 0.f;
    if (EPI == 1) { sc = bn_s[cc]; tc = bn_t[cc]; }
    #pragma unroll
    for (int mi = 0; mi < 4; ++mi) {
      int rbase = row0 + wr * 64 + mi * 16 + (lane >> 4) * 4;
      #pragma unroll
      for (int r = 0; r < 4; ++r) {
        int rr = rbase + r;
        if (rr < M) {
          float v = acc[mi][ni][r];
          if (EPI == 1) {
            v = fmaxf(v * sc + tc, 0.f);
            unsigned short hv = f2bf(v);
            O1[(size_t)rr * N + cc] = hv;
            O2[(size_t)rr * N + cc] = f2bf(v - bf2f(hv));
          } else {
            C[(size_t)rr * N + cc] = v;
            O1[(size_t)rr * N + cc] = f2bf(v);
          }
        }
      }
    }
  }
}

// ---------- agg2: out = A_norm*h2 + b2. Quarter-wave per edge, ushort4 per lane. ----------

__global__ __launch_bounds__(256) void agg2_k(
    const int* __restrict__ ptr, const int* __restrict__ ss,
    const float* __restrict__ dinv, const float* __restrict__ h2,
    const unsigned short* __restrict__ h2bf, const float* __restrict__ b2,
    float* __restrict__ out, int n) {
  int w = threadIdx.x >> 6;
  int lane = threadIdx.x & 63;
  int i = blockIdx.x * 4 + w;
  if (i >= n) return;
  int sub = lane >> 4;       // 0..3: edge phase
  int f4 = (lane & 15) * 4;  // 4 features per lane
  int beg = ptr[i], end = ptr[i + 1];
  float di = dinv[i];
  float a[4] = {};
  int e = beg;
  for (; e + 16 <= end; e += 16) {
    int s0 = ss[e + sub], s1 = ss[e + 4 + sub], s2 = ss[e + 8 + sub], s3 = ss[e + 12 + sub];
    float c0 = dinv[s0], c1 = dinv[s1], c2 = dinv[s2], c3 = dinv[s3];
    ushort4 v0 = *reinterpret_cast<const ushort4*>(h2bf + (size_t)s0 * CDIM + f4);
    ushort4 v1 = *reinterpret_cast<const ushort4*>(h2bf + (size_t)s1 * CDIM + f4);
    ushort4 v2 = *reinterpret_cast<const ushort4*>(h2bf + (size_t)s2 * CDIM + f4);
    ushort4 v3 = *reinterpret_cast<const ushort4*>(h2bf + (size_t)s3 * CDIM + f4);
    a[0] += c0 * bf2f(v0.x) + c1 * bf2f(v1.x) + c2 * bf2f(v2.x) + c3 * bf2f(v3.x);
    a[1] += c0 * bf2f(v0.y) + c1 * bf2f(v1.y) + c2 * bf2f(v2.y) + c3 * bf2f(v3.y);
    a[2] += c0 * bf2f(v0.z) + c1 * bf2f(v1.z) + c2 * bf2f(v2.z) + c3 * bf2f(v3.z);
    a[3] += c0 * bf2f(v0.w) + c1 * bf2f(v1.w) + c2 * bf2f(v2.w) + c3 * bf2f(v3.w);
  }
  for (; e < end; e += 4) {
    int idx = e + sub;
    if (idx < end) {
      int s = ss[idx];
      float c = dinv[s];
      ushort4 v = *reinterpret_cast<const ushort4*>(h2bf + (size_t)s * CDIM + f4);
      a[0] += c * bf2f(v.x); a[1] += c * bf2f(v.y);
      a[2] += c * bf2f(v.z); a[3] += c * bf2f(v.w);
    }
  }
  #pragma unroll
  for (int k = 0; k < 4; ++k) {
    a[k] += __shfl_xor(a[k], 16);
    a[k] += __shfl_xor(a[k], 32);
  }
  if (sub == 0) {
    float4 self = *reinterpret_cast<const float4*>(h2 + (size_t)i * CDIM + f4);
    float4 vb2 = *reinterpret_cast<const float4*>(b2 + f4);
    float di2 = di * di;
    float4 o;
    o.x = a[0] * di + self.x * di2 + vb2.x;
    o.y = a[1] * di + self.y * di2 + vb2.y;
    o.z = a[2] * di + self.z * di2 + vb2.z;
    o.w = a[3] * di + self.w * di2 + vb2.w;
    *reinterpret_cast<float4*>(out + (size_t)i * CDIM + f4) = o;
  }
}

extern "C" void kernel_launch(void* const* d_in, const int* in_sizes, int n_in,
                              void* d_out, int out_size, void* d_ws, size_t ws_size,
                              hipStream_t stream) {
  const float* x     = (const float*)d_in[0];
  const int*   ei    = (const int*)d_in[1];
  const float* W1    = (const float*)d_in[2];
  const float* b1    = (const float*)d_in[3];
  const float* gamma = (const float*)d_in[4];
  const float* beta  = (const float*)d_in[5];
  const float* rm    = (const float*)d_in[6];
  const float* rv    = (const float*)d_in[7];
  const float* W2    = (const float*)d_in[8];
  const float* b2    = (const float*)d_in[9];
  float* out = (float*)d_out;

  const int* src = ei;
  const int* dst = ei + NEDGES;

  char* ws = (char*)d_ws;
  auto alloc = [&](size_t bytes) {
    void* p = ws;
    ws += (bytes + 255) & ~(size_t)255;
    return p;
  };
  const int NB = (NNODES + 511) / 512;
  const int EG = (NEDGES + 255) / 256;
  int*   cnt_sub    = (int*)alloc((size_t)NSUB * NNODES * 4);
  int*   cursor_sub = (int*)alloc((size_t)NSUB * NNODES * 4);
  int*   cnt      = (int*)alloc((size_t)NNODES * 4);
  int*   ptr      = (int*)alloc(((size_t)NNODES + 1) * 4);
  float* dinv     = (float*)alloc((size_t)NNODES * 4);
  int*   s_sorted = (int*)alloc((size_t)NEDGES * 4);
  int*   partial  = (int*)alloc((size_t)NB * 4);
  int*   pscan    = (int*)alloc((size_t)NB * 4);
  unsigned short* xbf    = (unsigned short*)alloc((size_t)NNODES * FIN * 2);  // -> houtHi
  unsigned short* xhHi   = (unsigned short*)alloc((size_t)NNODES * FIN * 2);  // -> h2 (fp32)
  unsigned short* houtLo = (unsigned short*)alloc((size_t)NNODES * HDIM * 2);
  unsigned short* h2bf   = (unsigned short*)alloc((size_t)NNODES * CDIM * 2);
  unsigned short* w1thi  = (unsigned short*)alloc((size_t)HDIM * FIN * 2);
  unsigned short* w1tlo  = (unsigned short*)alloc((size_t)HDIM * FIN * 2);
  unsigned short* w2thi  = (unsigned short*)alloc((size_t)CDIM * HDIM * 2);
  unsigned short* w2tlo  = (unsigned short*)alloc((size_t)CDIM * HDIM * 2);
  float* bn_s = (float*)alloc(HDIM * 4);
  float* bn_t = (float*)alloc(HDIM * 4);

  unsigned short* houtHi = xbf;           // alias: xbf dead after agg_x
  float*          h2     = (float*)xhHi;  // alias: xhat dead after GEMM1 (25.6MB < 51.2MB)

  // CSR build, 8-way sub-binned
  hipMemsetAsync(cnt_sub, 0, (size_t)NSUB * NNODES * 4, stream);
  hist_k<<<EG, 256, 0, stream>>>(dst, cnt_sub, NEDGES);
  reduce_k<<<(NNODES + 255) / 256, 256, 0, stream>>>(cnt_sub, cnt, NNODES);
  partial_k<<<NB, 256, 0, stream>>>(cnt, partial, NNODES);
  scanpart_k<<<1, 256, 0, stream>>>(partial, pscan, NB);
  apply_k<<<NB, 256, 0, stream>>>(cnt, pscan, ptr, dinv, NNODES);
  suboff_k<<<(NNODES + 255) / 256, 256, 0, stream>>>(cnt_sub, ptr, cursor_sub, NNODES);
  scatter_k<<<EG, 256, 0, stream>>>(src, dst, cursor_sub, s_sorted, NEDGES);

  // prep
  xbf_k<<<12800, 256, 0, stream>>>(x, xbf, NNODES * FIN / 4);
  bn_prep_k<<<1, HDIM, 0, stream>>>(b1, gamma, beta, rm, rv, bn_s, bn_t);
  split_wt_k<<<HDIM, 256, 0, stream>>>(W1, w1thi, w1tlo, FIN, HDIM);
  split_wt_k<<<CDIM, 256, 0, stream>>>(W2, w2thi, w2tlo, HDIM, CDIM);

  // layer 1 reordered: xhat = A_norm*x (bf16), hout = relu(BN(xhat@W1+b1)) in GEMM epilogue
  agg_x_k<<<(NNODES + 3) / 4, 256, 0, stream>>>(ptr, s_sorted, dinv, xbf, xhHi, NNODES);
  gemm_split_k<128, 1, false><<<dim3((NNODES + 127) / 128, HDIM / 128), 256, 0, stream>>>(
      xhHi, nullptr, w1thi, w1tlo, nullptr, houtHi, houtLo, bn_s, bn_t, NNODES, HDIM, FIN);

  // layer 2: h2 = hout@W2 (3-term), out = A_norm*h2 + b2
  gemm_split_k<64, 2, true><<<dim3((NNODES + 127) / 128, 1), 256, 0, stream>>>(
      houtHi, houtLo, w2thi, w2tlo, h2, h2bf, nullptr, nullptr, nullptr, NNODES, CDIM, HDIM);
  agg2_k<<<(NNODES + 3) / 4, 256, 0, stream>>>(ptr, s_sorted, dinv, h2, h2bf, b2, out, NNODES);
}

// Round 7
// 356.522 us; speedup vs baseline: 20.1942x; 1.4218x over previous
//
#include <hip/hip_runtime.h>

#define NNODES 100000
#define NEDGES 1600000
#define FIN 256
#define HDIM 256
#define CDIM 64
#define BN_EPS 1e-5f

// radix-CSR params
#define EPB 4096                       // edges per phase-1 block
#define NBLK ((NEDGES + EPB - 1) / EPB)  // 391
#define NSEGS ((NNODES + 255) / 256)     // 391 segments of 256 nodes
#define SEGCAP 4608                    // max edges per segment (mean 4096, sigma 64)

typedef __attribute__((ext_vector_type(8))) short short8;
typedef __attribute__((ext_vector_type(8))) unsigned short ushort8_t;
typedef __attribute__((ext_vector_type(4))) float f32x4;

static __device__ __forceinline__ unsigned short f2bf(float f) {
  unsigned u = __float_as_uint(f);
  u += 0x7FFF + ((u >> 16) & 1);
  return (unsigned short)(u >> 16);
}
static __device__ __forceinline__ float bf2f(unsigned short h) {
  return __uint_as_float(((unsigned)h) << 16);
}

// ---------- CSR build via 2-phase LDS radix (no global atomics) ----------

// Phase 1a: per-block seg histogram; per-edge rank word = (seg<<21)|(dst&255)<<13|rank
__global__ __launch_bounds__(256) void p1hist_k(const int* __restrict__ dst,
                                                unsigned* __restrict__ rank,
                                                int* __restrict__ bh) {
  __shared__ int lh[NSEGS];
  int b = blockIdx.x, t = threadIdx.x;
  for (int j = t; j < NSEGS; j += 256) lh[j] = 0;
  __syncthreads();
  int base = b * EPB;
  #pragma unroll
  for (int it = 0; it < EPB / 256; ++it) {
    int i = base + it * 256 + t;
    if (i < NEDGES) {
      int d = dst[i];
      int seg = d >> 8;
      int r = atomicAdd(&lh[seg], 1);
      rank[i] = ((unsigned)seg << 21) | ((unsigned)(d & 255) << 13) | (unsigned)r;
    }
  }
  __syncthreads();
  for (int j = t; j < NSEGS; j += 256) bh[j * NBLK + b] = lh[j];  // transposed
}

// Phase 1b: per-seg exclusive prefix over blocks; seg totals
__global__ __launch_bounds__(512) void p1scan_k(const int* __restrict__ bh,
                                                int* __restrict__ rowpref,
                                                int* __restrict__ segtot) {
  __shared__ int sm[512];
  int s = blockIdx.x, t = threadIdx.x;
  int v = (t < NBLK) ? bh[s * NBLK + t] : 0;
  sm[t] = v;
  __syncthreads();
  for (int off = 1; off < 512; off <<= 1) {
    int x = (t >= off) ? sm[t - off] : 0;
    __syncthreads();
    sm[t] += x;
    __syncthreads();
  }
  if (t < NBLK) rowpref[s * NBLK + t] = sm[t] - v;
  if (t == NBLK - 1) segtot[s] = sm[t];
}

__global__ __launch_bounds__(512) void segscan_k(const int* __restrict__ segtot,
                                                 int* __restrict__ segbase) {
  __shared__ int sm[512];
  int t = threadIdx.x;
  int v = (t < NSEGS) ? segtot[t] : 0;
  sm[t] = v;
  __syncthreads();
  for (int off = 1; off < 512; off <<= 1) {
    int x = (t >= off) ? sm[t - off] : 0;
    __syncthreads();
    sm[t] += x;
    __syncthreads();
  }
  if (t < NSEGS) segbase[t] = sm[t] - v;
  if (t == 0) segbase[NSEGS] = NEDGES;
}

// Phase 1c: seg-sort block's edges in LDS, then write coalesced runs.
// esort word = (src<<8) | (dst&255)
__global__ __launch_bounds__(512) void p1scat_k(const int* __restrict__ src,
                                                const unsigned* __restrict__ rank,
                                                const int* __restrict__ rowpref,
                                                const int* __restrict__ segbase,
                                                unsigned* __restrict__ esort) {
  __shared__ int lh[512];      // hist, then reused as exclusive scan
  __shared__ int sc[512];      // scan workspace
  __shared__ int O[NSEGS];     // global offset per seg minus local start
  __shared__ unsigned sorted[EPB];
  __shared__ unsigned short segslot[EPB];
  int b = blockIdx.x, t = threadIdx.x;
  int base = b * EPB;
  lh[t] = 0;
  __syncthreads();
  unsigned wv[EPB / 512];
  #pragma unroll
  for (int it = 0; it < EPB / 512; ++it) {
    int i = base + it * 512 + t;
    wv[it] = 0xFFFFFFFFu;
    if (i < NEDGES) {
      wv[it] = rank[i];
      atomicAdd(&lh[wv[it] >> 21], 1);
    }
  }
  __syncthreads();
  int v = lh[t];
  sc[t] = v;
  __syncthreads();
  for (int off = 1; off < 512; off <<= 1) {
    int x = (t >= off) ? sc[t - off] : 0;
    __syncthreads();
    sc[t] += x;
    __syncthreads();
  }
  int excl = sc[t] - v;
  __syncthreads();
  lh[t] = excl;  // lh now: local exclusive start per seg
  if (t < NSEGS) O[t] = segbase[t] + rowpref[t * NBLK + b] - excl;
  __syncthreads();
  #pragma unroll
  for (int it = 0; it < EPB / 512; ++it) {
    int i = base + it * 512 + t;
    if (i < NEDGES) {
      unsigned w = wv[it];
      int seg = w >> 21;
      int r = w & 8191;
      int d8 = (w >> 13) & 255;
      int slot = lh[seg] + r;
      sorted[slot] = ((unsigned)src[i] << 8) | (unsigned)d8;
      segslot[slot] = (unsigned short)seg;
    }
  }
  __syncthreads();
  int nE = NEDGES - base;
  if (nE > EPB) nE = EPB;
  for (int j = t; j < nE; j += 512) esort[O[segslot[j]] + j] = sorted[j];
}

// Phase 2: per-seg counting sort by dst&255 in LDS; emit s_sorted/ptr/dinv coalesced.
__global__ __launch_bounds__(256) void p2_k(const unsigned* __restrict__ esort,
                                            const int* __restrict__ segtot,
                                            const int* __restrict__ segbase,
                                            int* __restrict__ s_sorted,
                                            int* __restrict__ ptr,
                                            float* __restrict__ dinv) {
  __shared__ unsigned ebuf[SEGCAP];
  __shared__ unsigned short lrank[SEGCAP];
  __shared__ int outbuf[SEGCAP];
  __shared__ int lcnt[256];
  __shared__ int sm[256];
  __shared__ int nstart[256];
  int s = blockIdx.x, t = threadIdx.x;
  int base = segbase[s];
  int cntE = segtot[s];
  if (cntE > SEGCAP) cntE = SEGCAP;
  for (int j = t; j < cntE; j += 256) ebuf[j] = esort[base + j];
  lcnt[t] = 0;
  __syncthreads();
  for (int j = t; j < cntE; j += 256) {
    int d8 = ebuf[j] & 255;
    lrank[j] = (unsigned short)atomicAdd(&lcnt[d8], 1);
  }
  __syncthreads();
  int v = lcnt[t];
  sm[t] = v;
  __syncthreads();
  for (int off = 1; off < 256; off <<= 1) {
    int x = (t >= off) ? sm[t - off] : 0;
    __syncthreads();
    sm[t] += x;
    __syncthreads();
  }
  nstart[t] = sm[t] - v;
  int node = s * 256 + t;
  if (node < NNODES) {
    ptr[node] = base + sm[t] - v;
    dinv[node] = rsqrtf((float)v + 1.0f);
  }
  __syncthreads();
  for (int j = t; j < cntE; j += 256) {
    unsigned w = ebuf[j];
    outbuf[nstart[w & 255] + lrank[j]] = (int)(w >> 8);
  }
  __syncthreads();
  for (int j = t; j < cntE; j += 256) s_sorted[base + j] = outbuf[j];
  if (s == 0 && t == 0) ptr[NNODES] = NEDGES;
}

// ---------- conversions / prep ----------

__global__ void xbf_k(const float* __restrict__ x, unsigned short* __restrict__ xbf, int n4) {
  int i = blockIdx.x * blockDim.x + threadIdx.x;
  int stride = gridDim.x * blockDim.x;
  for (; i < n4; i += stride) {
    float4 v = reinterpret_cast<const float4*>(x)[i];
    reinterpret_cast<ushort4*>(xbf)[i] =
        make_ushort4(f2bf(v.x), f2bf(v.y), f2bf(v.z), f2bf(v.w));
  }
}

// W[K][N] fp32 -> Wt[N][K] bf16 hi/lo (tiny)
__global__ void split_wt_k(const float* __restrict__ W, unsigned short* __restrict__ hi,
                           unsigned short* __restrict__ lo, int K, int N) {
  int n = blockIdx.x;
  for (int k = threadIdx.x; k < K; k += blockDim.x) {
    float v = W[(size_t)k * N + n];
    unsigned short h = f2bf(v);
    hi[(size_t)n * K + k] = h;
    lo[(size_t)n * K + k] = f2bf(v - bf2f(h));
  }
}

__global__ void bn_prep_k(const float* __restrict__ b1, const float* __restrict__ gamma,
                          const float* __restrict__ beta, const float* __restrict__ rm,
                          const float* __restrict__ rv, float* __restrict__ bn_s,
                          float* __restrict__ bn_t) {
  int f = threadIdx.x;
  float s = gamma[f] * rsqrtf(rv[f] + BN_EPS);
  bn_s[f] = s;
  bn_t[f] = (b1[f] - rm[f]) * s + beta[f];
}

// ---------- agg_x: xhat = A_norm * x. Half-wave per edge, ushort8 (16B) per lane. ----------

__global__ __launch_bounds__(256) void agg_x_k(
    const int* __restrict__ ptr, const int* __restrict__ ss,
    const float* __restrict__ dinv, const unsigned short* __restrict__ xbf,
    unsigned short* __restrict__ xhHi, int n) {
  int w = threadIdx.x >> 6;
  int lane = threadIdx.x & 63;
  int i = blockIdx.x * 4 + w;
  if (i >= n) return;
  int sub = lane >> 5;       // 0: even edges, 1: odd edges
  int f8 = (lane & 31) * 8;  // 8 features per lane
  int beg = ptr[i], end = ptr[i + 1];
  float di = dinv[i];
  float a[8] = {};
  int e = beg;
  for (; e + 8 <= end; e += 8) {
    int s0 = ss[e + sub], s1 = ss[e + 2 + sub], s2 = ss[e + 4 + sub], s3 = ss[e + 6 + sub];
    float c0 = dinv[s0], c1 = dinv[s1], c2 = dinv[s2], c3 = dinv[s3];
    ushort8_t v0 = *reinterpret_cast<const ushort8_t*>(xbf + (size_t)s0 * FIN + f8);
    ushort8_t v1 = *reinterpret_cast<const ushort8_t*>(xbf + (size_t)s1 * FIN + f8);
    ushort8_t v2 = *reinterpret_cast<const ushort8_t*>(xbf + (size_t)s2 * FIN + f8);
    ushort8_t v3 = *reinterpret_cast<const ushort8_t*>(xbf + (size_t)s3 * FIN + f8);
    #pragma unroll
    for (int k = 0; k < 8; ++k)
      a[k] += c0 * bf2f(v0[k]) + c1 * bf2f(v1[k]) + c2 * bf2f(v2[k]) + c3 * bf2f(v3[k]);
  }
  for (; e < end; e += 2) {
    int idx = e + sub;
    if (idx < end) {
      int s = ss[idx];
      float c = dinv[s];
      ushort8_t v = *reinterpret_cast<const ushort8_t*>(xbf + (size_t)s * FIN + f8);
      #pragma unroll
      for (int k = 0; k < 8; ++k) a[k] += c * bf2f(v[k]);
    }
  }
  #pragma unroll
  for (int k = 0; k < 8; ++k) a[k] += __shfl_xor(a[k], 32);
  if (sub == 0) {
    ushort8_t vs = *reinterpret_cast<const ushort8_t*>(xbf + (size_t)i * FIN + f8);
    float di2 = di * di;
    ushort8_t o;
    #pragma unroll
    for (int k = 0; k < 8; ++k) o[k] = f2bf(a[k] * di + bf2f(vs[k]) * di2);
    *reinterpret_cast<ushort8_t*>(xhHi + (size_t)i * FIN + f8) = o;
  }
}

// ---------- split-bf16 MFMA GEMM: C = A*Bt^T. BM=128, BK=64. ----------
// ALO: 3-term (AhiBhi+AhiBlo+AloBhi); else 2-term (AhiBhi+AhiBlo).
// EPI=1: O1 = bf16(relu(v*bn_s+bn_t)) hi, O2 = lo  (GEMM1)
// EPI=2: C fp32, O1 = bf16(v)                       (GEMM2)

template <int BN, int EPI, bool ALO>
__global__ __launch_bounds__(256) void gemm_split_k(
    const unsigned short* __restrict__ Ahi, const unsigned short* __restrict__ Alo,
    const unsigned short* __restrict__ Bhi, const unsigned short* __restrict__ Blo,
    float* __restrict__ C, unsigned short* __restrict__ O1,
    unsigned short* __restrict__ O2, const float* __restrict__ bn_s,
    const float* __restrict__ bn_t, int M, int N, int K) {
  constexpr int WC = BN / 32;
  constexpr int ASZ = (ALO ? 2 : 1) * 128 * 64;
  __shared__ unsigned short smem[ASZ + 2 * BN * 64];
  unsigned short* aHi = smem;
  unsigned short* aLo = smem + 128 * 64;  // only if ALO
  unsigned short* bHi = smem + ASZ;
  unsigned short* bLo = bHi + BN * 64;

  const int tid = threadIdx.x;
  const int w = tid >> 6;
  const int lane = tid & 63;
  const int wr = w >> 1, wc = w & 1;
  const int row0 = blockIdx.x * 128;
  const int col0 = blockIdx.y * BN;

  f32x4 acc[4][WC];
  #pragma unroll
  for (int mi = 0; mi < 4; ++mi)
    #pragma unroll
    for (int ni = 0; ni < WC; ++ni) {
      f32x4 z = {0.f, 0.f, 0.f, 0.f};
      acc[mi][ni] = z;
    }

  auto stage = [&](const unsigned short* G, unsigned short* Ld, int rows, int gr0,
                   int maxRow, int k0) {
    for (int i = 0; i < rows / 32; ++i) {
      int chunk = i * 256 + tid;
      int r = chunk >> 3;
      int c = chunk & 7;
      int cs = c ^ (r & 7);
      int gr = gr0 + r;
      if (gr > maxRow) gr = maxRow;
      const unsigned short* gp = G + (size_t)gr * K + k0 + cs * 8;
      unsigned short* lp = Ld + (i * 256 + w * 64) * 8;
      __builtin_amdgcn_global_load_lds((const __attribute__((address_space(1))) void*)gp,
                                       (__attribute__((address_space(3))) void*)lp, 16, 0, 0);
    }
  };

  for (int k0 = 0; k0 < K; k0 += 64) {
    stage(Ahi, aHi, 128, row0, M - 1, k0);
    if constexpr (ALO) stage(Alo, aLo, 128, row0, M - 1, k0);
    stage(Bhi, bHi, BN, col0, N - 1, k0);
    stage(Blo, bLo, BN, col0, N - 1, k0);
    __syncthreads();
    #pragma unroll
    for (int kk = 0; kk < 2; ++kk) {
      short8 ah[4], al[4], bh[WC], bl[WC];
      #pragma unroll
      for (int mi = 0; mi < 4; ++mi) {
        int lr = wr * 64 + mi * 16 + (lane & 15);
        int slot = (kk * 4 + (lane >> 4)) ^ (lr & 7);
        int eo = lr * 64 + slot * 8;
        ah[mi] = *reinterpret_cast<const short8*>(aHi + eo);
        if constexpr (ALO) al[mi] = *reinterpret_cast<const short8*>(aLo + eo);
      }
      #pragma unroll
      for (int ni = 0; ni < WC; ++ni) {
        int lr = wc * (BN / 2) + ni * 16 + (lane & 15);
        int slot = (kk * 4 + (lane >> 4)) ^ (lr & 7);
        int eo = lr * 64 + slot * 8;
        bh[ni] = *reinterpret_cast<const short8*>(bHi + eo);
        bl[ni] = *reinterpret_cast<const short8*>(bLo + eo);
      }
      #pragma unroll
      for (int mi = 0; mi < 4; ++mi)
        #pragma unroll
        for (int ni = 0; ni < WC; ++ni) {
          acc[mi][ni] = __builtin_amdgcn_mfma_f32_16x16x32_bf16(ah[mi], bh[ni], acc[mi][ni], 0, 0, 0);
          acc[mi][ni] = __builtin_amdgcn_mfma_f32_16x16x32_bf16(ah[mi], bl[ni], acc[mi][ni], 0, 0, 0);
          if constexpr (ALO)
            acc[mi][ni] = __builtin_amdgcn_mfma_f32_16x16x32_bf16(al[mi], bh[ni], acc[mi][ni], 0, 0, 0);
        }
    }
    __syncthreads();
  }

  // C/D layout: col = lane&15, row = (lane>>4)*4 + r
  #pragma unroll
  for (int ni = 0; ni < WC; ++ni) {
    int cc = col0 + wc * (BN / 2) + ni * 16 + (lane & 15);
    float sc = 0.f, tc = 0.f;
    if (EPI == 1) { sc = bn_s[cc]; tc = bn_t[cc]; }
    #pragma unroll
    for (int mi = 0; mi < 4; ++mi) {
      int rbase = row0 + wr * 64 + mi * 16 + (lane >> 4) * 4;
      #pragma unroll
      for (int r = 0; r < 4; ++r) {
        int rr = rbase + r;
        if (rr < M) {
          float v = acc[mi][ni][r];
          if (EPI == 1) {
            v = fmaxf(v * sc + tc, 0.f);
            unsigned short hv = f2bf(v);
            O1[(size_t)rr * N + cc] = hv;
            O2[(size_t)rr * N + cc] = f2bf(v - bf2f(hv));
          } else {
            C[(size_t)rr * N + cc] = v;
            O1[(size_t)rr * N + cc] = f2bf(v);
          }
        }
      }
    }
  }
}

// ---------- agg2: out = A_norm*h2 + b2. Quarter-wave per edge, ushort4 per lane. ----------

__global__ __launch_bounds__(256) void agg2_k(
    const int* __restrict__ ptr, const int* __restrict__ ss,
    const float* __restrict__ dinv, const float* __restrict__ h2,
    const unsigned short* __restrict__ h2bf, const float* __restrict__ b2,
    float* __restrict__ out, int n) {
  int w = threadIdx.x >> 6;
  int lane = threadIdx.x & 63;
  int i = blockIdx.x * 4 + w;
  if (i >= n) return;
  int sub = lane >> 4;       // 0..3: edge phase
  int f4 = (lane & 15) * 4;  // 4 features per lane
  int beg = ptr[i], end = ptr[i + 1];
  float di = dinv[i];
  float a[4] = {};
  int e = beg;
  for (; e + 16 <= end; e += 16) {
    int s0 = ss[e + sub], s1 = ss[e + 4 + sub], s2 = ss[e + 8 + sub], s3 = ss[e + 12 + sub];
    float c0 = dinv[s0], c1 = dinv[s1], c2 = dinv[s2], c3 = dinv[s3];
    ushort4 v0 = *reinterpret_cast<const ushort4*>(h2bf + (size_t)s0 * CDIM + f4);
    ushort4 v1 = *reinterpret_cast<const ushort4*>(h2bf + (size_t)s1 * CDIM + f4);
    ushort4 v2 = *reinterpret_cast<const ushort4*>(h2bf + (size_t)s2 * CDIM + f4);
    ushort4 v3 = *reinterpret_cast<const ushort4*>(h2bf + (size_t)s3 * CDIM + f4);
    a[0] += c0 * bf2f(v0.x) + c1 * bf2f(v1.x) + c2 * bf2f(v2.x) + c3 * bf2f(v3.x);
    a[1] += c0 * bf2f(v0.y) + c1 * bf2f(v1.y) + c2 * bf2f(v2.y) + c3 * bf2f(v3.y);
    a[2] += c0 * bf2f(v0.z) + c1 * bf2f(v1.z) + c2 * bf2f(v2.z) + c3 * bf2f(v3.z);
    a[3] += c0 * bf2f(v0.w) + c1 * bf2f(v1.w) + c2 * bf2f(v2.w) + c3 * bf2f(v3.w);
  }
  for (; e < end; e += 4) {
    int idx = e + sub;
    if (idx < end) {
      int s = ss[idx];
      float c = dinv[s];
      ushort4 v = *reinterpret_cast<const ushort4*>(h2bf + (size_t)s * CDIM + f4);
      a[0] += c * bf2f(v.x); a[1] += c * bf2f(v.y);
      a[2] += c * bf2f(v.z); a[3] += c * bf2f(v.w);
    }
  }
  #pragma unroll
  for (int k = 0; k < 4; ++k) {
    a[k] += __shfl_xor(a[k], 16);
    a[k] += __shfl_xor(a[k], 32);
  }
  if (sub == 0) {
    float4 self = *reinterpret_cast<const float4*>(h2 + (size_t)i * CDIM + f4);
    float4 vb2 = *reinterpret_cast<const float4*>(b2 + f4);
    float di2 = di * di;
    float4 o;
    o.x = a[0] * di + self.x * di2 + vb2.x;
    o.y = a[1] * di + self.y * di2 + vb2.y;
    o.z = a[2] * di + self.z * di2 + vb2.z;
    o.w = a[3] * di + self.w * di2 + vb2.w;
    *reinterpret_cast<float4*>(out + (size_t)i * CDIM + f4) = o;
  }
}

extern "C" void kernel_launch(void* const* d_in, const int* in_sizes, int n_in,
                              void* d_out, int out_size, void* d_ws, size_t ws_size,
                              hipStream_t stream) {
  const float* x     = (const float*)d_in[0];
  const int*   ei    = (const int*)d_in[1];
  const float* W1    = (const float*)d_in[2];
  const float* b1    = (const float*)d_in[3];
  const float* gamma = (const float*)d_in[4];
  const float* beta  = (const float*)d_in[5];
  const float* rm    = (const float*)d_in[6];
  const float* rv    = (const float*)d_in[7];
  const float* W2    = (const float*)d_in[8];
  const float* b2    = (const float*)d_in[9];
  float* out = (float*)d_out;

  const int* src = ei;
  const int* dst = ei + NEDGES;

  char* ws = (char*)d_ws;
  auto alloc = [&](size_t bytes) {
    void* p = ws;
    ws += (bytes + 255) & ~(size_t)255;
    return p;
  };
  unsigned* rank    = (unsigned*)alloc((size_t)NEDGES * 4);
  unsigned* esort   = (unsigned*)alloc((size_t)NEDGES * 4);
  int*   bh       = (int*)alloc((size_t)NSEGS * NBLK * 4);
  int*   rowpref  = (int*)alloc((size_t)NSEGS * NBLK * 4);
  int*   segtot   = (int*)alloc((size_t)NSEGS * 4);
  int*   segbase  = (int*)alloc(((size_t)NSEGS + 1) * 4);
  int*   ptr      = (int*)alloc(((size_t)NNODES + 1) * 4);
  float* dinv     = (float*)alloc((size_t)NNODES * 4);
  int*   s_sorted = (int*)alloc((size_t)NEDGES * 4);
  unsigned short* xbf    = (unsigned short*)alloc((size_t)NNODES * FIN * 2);  // -> houtHi
  unsigned short* xhHi   = (unsigned short*)alloc((size_t)NNODES * FIN * 2);  // -> h2 (fp32)
  unsigned short* houtLo = (unsigned short*)alloc((size_t)NNODES * HDIM * 2);
  unsigned short* h2bf   = (unsigned short*)alloc((size_t)NNODES * CDIM * 2);
  unsigned short* w1thi  = (unsigned short*)alloc((size_t)HDIM * FIN * 2);
  unsigned short* w1tlo  = (unsigned short*)alloc((size_t)HDIM * FIN * 2);
  unsigned short* w2thi  = (unsigned short*)alloc((size_t)CDIM * HDIM * 2);
  unsigned short* w2tlo  = (unsigned short*)alloc((size_t)CDIM * HDIM * 2);
  float* bn_s = (float*)alloc(HDIM * 4);
  float* bn_t = (float*)alloc(HDIM * 4);

  unsigned short* houtHi = xbf;           // alias: xbf dead after agg_x
  float*          h2     = (float*)xhHi;  // alias: xhat dead after GEMM1 (25.6MB < 51.2MB)

  // CSR build: 2-phase LDS radix (no global atomics)
  p1hist_k<<<NBLK, 256, 0, stream>>>(dst, rank, bh);
  p1scan_k<<<NSEGS, 512, 0, stream>>>(bh, rowpref, segtot);
  segscan_k<<<1, 512, 0, stream>>>(segtot, segbase);
  p1scat_k<<<NBLK, 512, 0, stream>>>(src, rank, rowpref, segbase, esort);
  p2_k<<<NSEGS, 256, 0, stream>>>(esort, segtot, segbase, s_sorted, ptr, dinv);

  // prep
  xbf_k<<<12800, 256, 0, stream>>>(x, xbf, NNODES * FIN / 4);
  bn_prep_k<<<1, HDIM, 0, stream>>>(b1, gamma, beta, rm, rv, bn_s, bn_t);
  split_wt_k<<<HDIM, 256, 0, stream>>>(W1, w1thi, w1tlo, FIN, HDIM);
  split_wt_k<<<CDIM, 256, 0, stream>>>(W2, w2thi, w2tlo, HDIM, CDIM);

  // layer 1 reordered: xhat = A_norm*x (bf16), hout = relu(BN(xhat@W1+b1)) in GEMM epilogue
  agg_x_k<<<(NNODES + 3) / 4, 256, 0, stream>>>(ptr, s_sorted, dinv, xbf, xhHi, NNODES);
  gemm_split_k<128, 1, false><<<dim3((NNODES + 127) / 128, HDIM / 128), 256, 0, stream>>>(
      xhHi, nullptr, w1thi, w1tlo, nullptr, houtHi, houtLo, bn_s, bn_t, NNODES, HDIM, FIN);

  // layer 2: h2 = hout@W2 (3-term), out = A_norm*h2 + b2
  gemm_split_k<64, 2, true><<<dim3((NNODES + 127) / 128, 1), 256, 0, stream>>>(
      houtHi, houtLo, w2thi, w2tlo, h2, h2bf, nullptr, nullptr, nullptr, NNODES, CDIM, HDIM);
  agg2_k<<<(NNODES + 3) / 4, 256, 0, stream>>>(ptr, s_sorted, dinv, h2, h2bf, b2, out, NNODES);
}

// Round 8
// 318.752 us; speedup vs baseline: 22.5871x; 1.1185x over previous
//
#include <hip/hip_runtime.h>

#define NNODES 100000
#define NEDGES 1600000
#define FIN 256
#define HDIM 256
#define CDIM 64
#define BN_EPS 1e-5f

// radix-CSR params
#define EPB 4096                         // edges per phase-1 block
#define NBLK ((NEDGES + EPB - 1) / EPB)  // 391
#define NSEGS ((NNODES + 255) / 256)     // 391 segments of 256 nodes
#define SEGCAP 4608                      // max edges per segment (mean 4096)
#define XBLK 1600                        // converter blocks fused into p1hist

typedef __attribute__((ext_vector_type(8))) short short8;
typedef __attribute__((ext_vector_type(8))) unsigned short ushort8_t;
typedef __attribute__((ext_vector_type(4))) float f32x4;

static __device__ __forceinline__ unsigned short f2bf(float f) {
  unsigned u = __float_as_uint(f);
  u += 0x7FFF + ((u >> 16) & 1);
  return (unsigned short)(u >> 16);
}
static __device__ __forceinline__ float bf2f(unsigned short h) {
  return __uint_as_float(((unsigned)h) << 16);
}

// ---------- CSR build via 2-phase LDS radix (no global atomics) ----------

// Phase 1a (fused): blocks < NBLK: per-block seg histogram + per-edge rank word;
// blocks >= NBLK: x -> bf16 convert (grid-stride).
__global__ __launch_bounds__(256) void p1hist_k(const int* __restrict__ dst,
                                                const float* __restrict__ x,
                                                unsigned* __restrict__ rank,
                                                int* __restrict__ bh,
                                                unsigned short* __restrict__ xbf) {
  __shared__ int lh[NSEGS];
  int b = blockIdx.x, t = threadIdx.x;
  if (b >= NBLK) {
    const int n4 = NNODES * FIN / 4;
    int i = (b - NBLK) * 256 + t;
    const int stride = XBLK * 256;
    for (; i < n4; i += stride) {
      float4 v = reinterpret_cast<const float4*>(x)[i];
      reinterpret_cast<ushort4*>(xbf)[i] =
          make_ushort4(f2bf(v.x), f2bf(v.y), f2bf(v.z), f2bf(v.w));
    }
    return;
  }
  for (int j = t; j < NSEGS; j += 256) lh[j] = 0;
  __syncthreads();
  int base = b * EPB;
  #pragma unroll
  for (int it = 0; it < EPB / 256; ++it) {
    int i = base + it * 256 + t;
    if (i < NEDGES) {
      int d = dst[i];
      int seg = d >> 8;
      int r = atomicAdd(&lh[seg], 1);
      rank[i] = ((unsigned)seg << 21) | ((unsigned)(d & 255) << 13) | (unsigned)r;
    }
  }
  __syncthreads();
  for (int j = t; j < NSEGS; j += 256) bh[j * NBLK + b] = lh[j];  // transposed
}

// Phase 1b (fused): blocks < NSEGS: per-seg exclusive prefix over blocks;
// blocks NSEGS..+HDIM: W1 col split; ..+CDIM: W2 col split; last: bn prep.
__global__ __launch_bounds__(512) void p1scan_k(
    const int* __restrict__ bh, int* __restrict__ rowpref, int* __restrict__ segtot,
    const float* __restrict__ W1, const float* __restrict__ W2,
    const float* __restrict__ b1, const float* __restrict__ gamma,
    const float* __restrict__ beta, const float* __restrict__ rm,
    const float* __restrict__ rv,
    unsigned short* __restrict__ w1thi, unsigned short* __restrict__ w1tlo,
    unsigned short* __restrict__ w2thi, unsigned short* __restrict__ w2tlo,
    float* __restrict__ bn_s, float* __restrict__ bn_t) {
  __shared__ int sm[512];
  int s = blockIdx.x, t = threadIdx.x;
  if (s >= NSEGS) {
    int j = s - NSEGS;
    if (j < HDIM) {  // W1 column j
      if (t < FIN) {
        float v = W1[(size_t)t * HDIM + j];
        unsigned short h = f2bf(v);
        w1thi[(size_t)j * FIN + t] = h;
        w1tlo[(size_t)j * FIN + t] = f2bf(v - bf2f(h));
      }
    } else if (j < HDIM + CDIM) {  // W2 column
      int n = j - HDIM;
      if (t < HDIM) {
        float v = W2[(size_t)t * CDIM + n];
        unsigned short h = f2bf(v);
        w2thi[(size_t)n * HDIM + t] = h;
        w2tlo[(size_t)n * HDIM + t] = f2bf(v - bf2f(h));
      }
    } else {  // bn prep
      if (t < HDIM) {
        float sc = gamma[t] * rsqrtf(rv[t] + BN_EPS);
        bn_s[t] = sc;
        bn_t[t] = (b1[t] - rm[t]) * sc + beta[t];
      }
    }
    return;
  }
  int v = (t < NBLK) ? bh[s * NBLK + t] : 0;
  sm[t] = v;
  __syncthreads();
  for (int off = 1; off < 512; off <<= 1) {
    int x = (t >= off) ? sm[t - off] : 0;
    __syncthreads();
    sm[t] += x;
    __syncthreads();
  }
  if (t < NBLK) rowpref[s * NBLK + t] = sm[t] - v;
  if (t == NBLK - 1) segtot[s] = sm[t];
}

__global__ __launch_bounds__(512) void segscan_k(const int* __restrict__ segtot,
                                                 int* __restrict__ segbase) {
  __shared__ int sm[512];
  int t = threadIdx.x;
  int v = (t < NSEGS) ? segtot[t] : 0;
  sm[t] = v;
  __syncthreads();
  for (int off = 1; off < 512; off <<= 1) {
    int x = (t >= off) ? sm[t - off] : 0;
    __syncthreads();
    sm[t] += x;
    __syncthreads();
  }
  if (t < NSEGS) segbase[t] = sm[t] - v;
  if (t == 0) segbase[NSEGS] = NEDGES;
}

// Phase 1c: seg-sort block's edges in LDS, then write coalesced runs.
// esort word = (src<<8) | (dst&255)
__global__ __launch_bounds__(512) void p1scat_k(const int* __restrict__ src,
                                                const unsigned* __restrict__ rank,
                                                const int* __restrict__ rowpref,
                                                const int* __restrict__ segbase,
                                                unsigned* __restrict__ esort) {
  __shared__ int lh[512];
  __shared__ int sc[512];
  __shared__ int O[NSEGS];
  __shared__ unsigned sorted[EPB];
  __shared__ unsigned short segslot[EPB];
  int b = blockIdx.x, t = threadIdx.x;
  int base = b * EPB;
  lh[t] = 0;
  __syncthreads();
  unsigned wv[EPB / 512];
  #pragma unroll
  for (int it = 0; it < EPB / 512; ++it) {
    int i = base + it * 512 + t;
    wv[it] = 0xFFFFFFFFu;
    if (i < NEDGES) {
      wv[it] = rank[i];
      atomicAdd(&lh[wv[it] >> 21], 1);
    }
  }
  __syncthreads();
  int v = lh[t];
  sc[t] = v;
  __syncthreads();
  for (int off = 1; off < 512; off <<= 1) {
    int x = (t >= off) ? sc[t - off] : 0;
    __syncthreads();
    sc[t] += x;
    __syncthreads();
  }
  int excl = sc[t] - v;
  __syncthreads();
  lh[t] = excl;
  if (t < NSEGS) O[t] = segbase[t] + rowpref[t * NBLK + b] - excl;
  __syncthreads();
  #pragma unroll
  for (int it = 0; it < EPB / 512; ++it) {
    int i = base + it * 512 + t;
    if (i < NEDGES) {
      unsigned w = wv[it];
      int seg = w >> 21;
      int r = w & 8191;
      int d8 = (w >> 13) & 255;
      int slot = lh[seg] + r;
      sorted[slot] = ((unsigned)src[i] << 8) | (unsigned)d8;
      segslot[slot] = (unsigned short)seg;
    }
  }
  __syncthreads();
  int nE = NEDGES - base;
  if (nE > EPB) nE = EPB;
  for (int j = t; j < nE; j += 512) esort[O[segslot[j]] + j] = sorted[j];
}

// Phase 2: per-seg counting sort by dst&255 in LDS; emit s_sorted/ptr/dinv coalesced.
__global__ __launch_bounds__(256) void p2_k(const unsigned* __restrict__ esort,
                                            const int* __restrict__ segtot,
                                            const int* __restrict__ segbase,
                                            int* __restrict__ s_sorted,
                                            int* __restrict__ ptr,
                                            float* __restrict__ dinv) {
  __shared__ unsigned ebuf[SEGCAP];
  __shared__ unsigned short lrank[SEGCAP];
  __shared__ int outbuf[SEGCAP];
  __shared__ int lcnt[256];
  __shared__ int sm[256];
  __shared__ int nstart[256];
  int s = blockIdx.x, t = threadIdx.x;
  int base = segbase[s];
  int cntE = segtot[s];
  if (cntE > SEGCAP) cntE = SEGCAP;
  for (int j = t; j < cntE; j += 256) ebuf[j] = esort[base + j];
  lcnt[t] = 0;
  __syncthreads();
  for (int j = t; j < cntE; j += 256) {
    int d8 = ebuf[j] & 255;
    lrank[j] = (unsigned short)atomicAdd(&lcnt[d8], 1);
  }
  __syncthreads();
  int v = lcnt[t];
  sm[t] = v;
  __syncthreads();
  for (int off = 1; off < 256; off <<= 1) {
    int x = (t >= off) ? sm[t - off] : 0;
    __syncthreads();
    sm[t] += x;
    __syncthreads();
  }
  nstart[t] = sm[t] - v;
  int node = s * 256 + t;
  if (node < NNODES) {
    ptr[node] = base + sm[t] - v;
    dinv[node] = rsqrtf((float)v + 1.0f);
  }
  __syncthreads();
  for (int j = t; j < cntE; j += 256) {
    unsigned w = ebuf[j];
    outbuf[nstart[w & 255] + lrank[j]] = (int)(w >> 8);
  }
  __syncthreads();
  for (int j = t; j < cntE; j += 256) s_sorted[base + j] = outbuf[j];
  if (s == 0 && t == 0) ptr[NNODES] = NEDGES;
}

// ---------- agg_x: xhat = A_norm * x. Half-wave per edge, ushort8 (16B) per lane. ----------

__global__ __launch_bounds__(256) void agg_x_k(
    const int* __restrict__ ptr, const int* __restrict__ ss,
    const float* __restrict__ dinv, const unsigned short* __restrict__ xbf,
    unsigned short* __restrict__ xhHi, int n) {
  int w = threadIdx.x >> 6;
  int lane = threadIdx.x & 63;
  int i = blockIdx.x * 4 + w;
  if (i >= n) return;
  int sub = lane >> 5;       // 0: even edges, 1: odd edges
  int f8 = (lane & 31) * 8;  // 8 features per lane
  int beg = ptr[i], end = ptr[i + 1];
  float di = dinv[i];
  float a[8] = {};
  int e = beg;
  for (; e + 8 <= end; e += 8) {
    int s0 = ss[e + sub], s1 = ss[e + 2 + sub], s2 = ss[e + 4 + sub], s3 = ss[e + 6 + sub];
    float c0 = dinv[s0], c1 = dinv[s1], c2 = dinv[s2], c3 = dinv[s3];
    ushort8_t v0 = *reinterpret_cast<const ushort8_t*>(xbf + (size_t)s0 * FIN + f8);
    ushort8_t v1 = *reinterpret_cast<const ushort8_t*>(xbf + (size_t)s1 * FIN + f8);
    ushort8_t v2 = *reinterpret_cast<const ushort8_t*>(xbf + (size_t)s2 * FIN + f8);
    ushort8_t v3 = *reinterpret_cast<const ushort8_t*>(xbf + (size_t)s3 * FIN + f8);
    #pragma unroll
    for (int k = 0; k < 8; ++k)
      a[k] += c0 * bf2f(v0[k]) + c1 * bf2f(v1[k]) + c2 * bf2f(v2[k]) + c3 * bf2f(v3[k]);
  }
  for (; e < end; e += 2) {
    int idx = e + sub;
    if (idx < end) {
      int s = ss[idx];
      float c = dinv[s];
      ushort8_t v = *reinterpret_cast<const ushort8_t*>(xbf + (size_t)s * FIN + f8);
      #pragma unroll
      for (int k = 0; k < 8; ++k) a[k] += c * bf2f(v[k]);
    }
  }
  #pragma unroll
  for (int k = 0; k < 8; ++k) a[k] += __shfl_xor(a[k], 32);
  if (sub == 0) {
    ushort8_t vs = *reinterpret_cast<const ushort8_t*>(xbf + (size_t)i * FIN + f8);
    float di2 = di * di;
    ushort8_t o;
    #pragma unroll
    for (int k = 0; k < 8; ++k) o[k] = f2bf(a[k] * di + bf2f(vs[k]) * di2);
    *reinterpret_cast<ushort8_t*>(xhHi + (size_t)i * FIN + f8) = o;
  }
}

// ---------- split-bf16 MFMA GEMM: C = A*Bt^T. BM=128, BK=64. ----------
// ALO: 3-term (AhiBhi+AhiBlo+AloBhi); else 2-term (AhiBhi+AhiBlo).
// EPI=1: O1 = bf16(relu(v*bn_s+bn_t))  (GEMM1)
// EPI=2: C fp32, O1 = bf16(v)          (GEMM2)

template <int BN, int EPI, bool ALO>
__global__ __launch_bounds__(256) void gemm_split_k(
    const unsigned short* __restrict__ Ahi, const unsigned short* __restrict__ Alo,
    const unsigned short* __restrict__ Bhi, const unsigned short* __restrict__ Blo,
    float* __restrict__ C, unsigned short* __restrict__ O1,
    const float* __restrict__ bn_s, const float* __restrict__ bn_t,
    int M, int N, int K) {
  constexpr int WC = BN / 32;
  constexpr int ASZ = (ALO ? 2 : 1) * 128 * 64;
  __shared__ unsigned short smem[ASZ + 2 * BN * 64];
  unsigned short* aHi = smem;
  unsigned short* aLo = smem + 128 * 64;  // only if ALO
  unsigned short* bHi = smem + ASZ;
  unsigned short* bLo = bHi + BN * 64;

  const int tid = threadIdx.x;
  const int w = tid >> 6;
  const int lane = tid & 63;
  const int wr = w >> 1, wc = w & 1;
  const int row0 = blockIdx.x * 128;
  const int col0 = blockIdx.y * BN;

  f32x4 acc[4][WC];
  #pragma unroll
  for (int mi = 0; mi < 4; ++mi)
    #pragma unroll
    for (int ni = 0; ni < WC; ++ni) {
      f32x4 z = {0.f, 0.f, 0.f, 0.f};
      acc[mi][ni] = z;
    }

  auto stage = [&](const unsigned short* G, unsigned short* Ld, int rows, int gr0,
                   int maxRow, int k0) {
    for (int i = 0; i < rows / 32; ++i) {
      int chunk = i * 256 + tid;
      int r = chunk >> 3;
      int c = chunk & 7;
      int cs = c ^ (r & 7);
      int gr = gr0 + r;
      if (gr > maxRow) gr = maxRow;
      const unsigned short* gp = G + (size_t)gr * K + k0 + cs * 8;
      unsigned short* lp = Ld + (i * 256 + w * 64) * 8;
      __builtin_amdgcn_global_load_lds((const __attribute__((address_space(1))) void*)gp,
                                       (__attribute__((address_space(3))) void*)lp, 16, 0, 0);
    }
  };

  for (int k0 = 0; k0 < K; k0 += 64) {
    stage(Ahi, aHi, 128, row0, M - 1, k0);
    if constexpr (ALO) stage(Alo, aLo, 128, row0, M - 1, k0);
    stage(Bhi, bHi, BN, col0, N - 1, k0);
    stage(Blo, bLo, BN, col0, N - 1, k0);
    __syncthreads();
    #pragma unroll
    for (int kk = 0; kk < 2; ++kk) {
      short8 ah[4], al[4], bh[WC], bl[WC];
      #pragma unroll
      for (int mi = 0; mi < 4; ++mi) {
        int lr = wr * 64 + mi * 16 + (lane & 15);
        int slot = (kk * 4 + (lane >> 4)) ^ (lr & 7);
        int eo = lr * 64 + slot * 8;
        ah[mi] = *reinterpret_cast<const short8*>(aHi + eo);
        if constexpr (ALO) al[mi] = *reinterpret_cast<const short8*>(aLo + eo);
      }
      #pragma unroll
      for (int ni = 0; ni < WC; ++ni) {
        int lr = wc * (BN / 2) + ni * 16 + (lane & 15);
        int slot = (kk * 4 + (lane >> 4)) ^ (lr & 7);
        int eo = lr * 64 + slot * 8;
        bh[ni] = *reinterpret_cast<const short8*>(bHi + eo);
        bl[ni] = *reinterpret_cast<const short8*>(bLo + eo);
      }
      #pragma unroll
      for (int mi = 0; mi < 4; ++mi)
        #pragma unroll
        for (int ni = 0; ni < WC; ++ni) {
          acc[mi][ni] = __builtin_amdgcn_mfma_f32_16x16x32_bf16(ah[mi], bh[ni], acc[mi][ni], 0, 0, 0);
          acc[mi][ni] = __builtin_amdgcn_mfma_f32_16x16x32_bf16(ah[mi], bl[ni], acc[mi][ni], 0, 0, 0);
          if constexpr (ALO)
            acc[mi][ni] = __builtin_amdgcn_mfma_f32_16x16x32_bf16(al[mi], bh[ni], acc[mi][ni], 0, 0, 0);
        }
    }
    __syncthreads();
  }

  // C/D layout: col = lane&15, row = (lane>>4)*4 + r
  #pragma unroll
  for (int ni = 0; ni < WC; ++ni) {
    int cc = col0 + wc * (BN / 2) + ni * 16 + (lane & 15);
    float sc = 0.f, tc = 0.f;
    if (EPI == 1) { sc = bn_s[cc]; tc = bn_t[cc]; }
    #pragma unroll
    for (int mi = 0; mi < 4; ++mi) {
      int rbase = row0 + wr * 64 + mi * 16 + (lane >> 4) * 4;
      #pragma unroll
      for (int r = 0; r < 4; ++r) {
        int rr = rbase + r;
        if (rr < M) {
          float v = acc[mi][ni][r];
          if (EPI == 1) {
            v = fmaxf(v * sc + tc, 0.f);
            O1[(size_t)rr * N + cc] = f2bf(v);
          } else {
            C[(size_t)rr * N + cc] = v;
            O1[(size_t)rr * N + cc] = f2bf(v);
          }
        }
      }
    }
  }
}

// ---------- agg2: out = A_norm*h2 + b2. Quarter-wave per edge, ushort4 per lane. ----------

__global__ __launch_bounds__(256) void agg2_k(
    const int* __restrict__ ptr, const int* __restrict__ ss,
    const float* __restrict__ dinv, const float* __restrict__ h2,
    const unsigned short* __restrict__ h2bf, const float* __restrict__ b2,
    float* __restrict__ out, int n) {
  int w = threadIdx.x >> 6;
  int lane = threadIdx.x & 63;
  int i = blockIdx.x * 4 + w;
  if (i >= n) return;
  int sub = lane >> 4;       // 0..3: edge phase
  int f4 = (lane & 15) * 4;  // 4 features per lane
  int beg = ptr[i], end = ptr[i + 1];
  float di = dinv[i];
  float a[4] = {};
  int e = beg;
  for (; e + 16 <= end; e += 16) {
    int s0 = ss[e + sub], s1 = ss[e + 4 + sub], s2 = ss[e + 8 + sub], s3 = ss[e + 12 + sub];
    float c0 = dinv[s0], c1 = dinv[s1], c2 = dinv[s2], c3 = dinv[s3];
    ushort4 v0 = *reinterpret_cast<const ushort4*>(h2bf + (size_t)s0 * CDIM + f4);
    ushort4 v1 = *reinterpret_cast<const ushort4*>(h2bf + (size_t)s1 * CDIM + f4);
    ushort4 v2 = *reinterpret_cast<const ushort4*>(h2bf + (size_t)s2 * CDIM + f4);
    ushort4 v3 = *reinterpret_cast<const ushort4*>(h2bf + (size_t)s3 * CDIM + f4);
    a[0] += c0 * bf2f(v0.x) + c1 * bf2f(v1.x) + c2 * bf2f(v2.x) + c3 * bf2f(v3.x);
    a[1] += c0 * bf2f(v0.y) + c1 * bf2f(v1.y) + c2 * bf2f(v2.y) + c3 * bf2f(v3.y);
    a[2] += c0 * bf2f(v0.z) + c1 * bf2f(v1.z) + c2 * bf2f(v2.z) + c3 * bf2f(v3.z);
    a[3] += c0 * bf2f(v0.w) + c1 * bf2f(v1.w) + c2 * bf2f(v2.w) + c3 * bf2f(v3.w);
  }
  for (; e < end; e += 4) {
    int idx = e + sub;
    if (idx < end) {
      int s = ss[idx];
      float c = dinv[s];
      ushort4 v = *reinterpret_cast<const ushort4*>(h2bf + (size_t)s * CDIM + f4);
      a[0] += c * bf2f(v.x); a[1] += c * bf2f(v.y);
      a[2] += c * bf2f(v.z); a[3] += c * bf2f(v.w);
    }
  }
  #pragma unroll
  for (int k = 0; k < 4; ++k) {
    a[k] += __shfl_xor(a[k], 16);
    a[k] += __shfl_xor(a[k], 32);
  }
  if (sub == 0) {
    float4 self = *reinterpret_cast<const float4*>(h2 + (size_t)i * CDIM + f4);
    float4 vb2 = *reinterpret_cast<const float4*>(b2 + f4);
    float di2 = di * di;
    float4 o;
    o.x = a[0] * di + self.x * di2 + vb2.x;
    o.y = a[1] * di + self.y * di2 + vb2.y;
    o.z = a[2] * di + self.z * di2 + vb2.z;
    o.w = a[3] * di + self.w * di2 + vb2.w;
    *reinterpret_cast<float4*>(out + (size_t)i * CDIM + f4) = o;
  }
}

extern "C" void kernel_launch(void* const* d_in, const int* in_sizes, int n_in,
                              void* d_out, int out_size, void* d_ws, size_t ws_size,
                              hipStream_t stream) {
  const float* x     = (const float*)d_in[0];
  const int*   ei    = (const int*)d_in[1];
  const float* W1    = (const float*)d_in[2];
  const float* b1    = (const float*)d_in[3];
  const float* gamma = (const float*)d_in[4];
  const float* beta  = (const float*)d_in[5];
  const float* rm    = (const float*)d_in[6];
  const float* rv    = (const float*)d_in[7];
  const float* W2    = (const float*)d_in[8];
  const float* b2    = (const float*)d_in[9];
  float* out = (float*)d_out;

  const int* src = ei;
  const int* dst = ei + NEDGES;

  char* ws = (char*)d_ws;
  auto alloc = [&](size_t bytes) {
    void* p = ws;
    ws += (bytes + 255) & ~(size_t)255;
    return p;
  };
  unsigned* rank    = (unsigned*)alloc((size_t)NEDGES * 4);
  unsigned* esort   = (unsigned*)alloc((size_t)NEDGES * 4);
  int*   bh       = (int*)alloc((size_t)NSEGS * NBLK * 4);
  int*   rowpref  = (int*)alloc((size_t)NSEGS * NBLK * 4);
  int*   segtot   = (int*)alloc((size_t)NSEGS * 4);
  int*   segbase  = (int*)alloc(((size_t)NSEGS + 1) * 4);
  int*   ptr      = (int*)alloc(((size_t)NNODES + 1) * 4);
  float* dinv     = (float*)alloc((size_t)NNODES * 4);
  int*   s_sorted = (int*)alloc((size_t)NEDGES * 4);
  unsigned short* xbf    = (unsigned short*)alloc((size_t)NNODES * FIN * 2);  // -> houtHi
  unsigned short* xhHi   = (unsigned short*)alloc((size_t)NNODES * FIN * 2);  // -> h2 (fp32)
  unsigned short* h2bf   = (unsigned short*)alloc((size_t)NNODES * CDIM * 2);
  unsigned short* w1thi  = (unsigned short*)alloc((size_t)HDIM * FIN * 2);
  unsigned short* w1tlo  = (unsigned short*)alloc((size_t)HDIM * FIN * 2);
  unsigned short* w2thi  = (unsigned short*)alloc((size_t)CDIM * HDIM * 2);
  unsigned short* w2tlo  = (unsigned short*)alloc((size_t)CDIM * HDIM * 2);
  float* bn_s = (float*)alloc(HDIM * 4);
  float* bn_t = (float*)alloc(HDIM * 4);

  unsigned short* houtHi = xbf;           // alias: xbf dead after agg_x
  float*          h2     = (float*)xhHi;  // alias: xhat dead after GEMM1 (25.6MB < 51.2MB)

  // CSR build (convert + weight-split fused into the low-occupancy passes)
  p1hist_k<<<NBLK + XBLK, 256, 0, stream>>>(dst, x, rank, bh, xbf);
  p1scan_k<<<NSEGS + HDIM + CDIM + 1, 512, 0, stream>>>(
      bh, rowpref, segtot, W1, W2, b1, gamma, beta, rm, rv,
      w1thi, w1tlo, w2thi, w2tlo, bn_s, bn_t);
  segscan_k<<<1, 512, 0, stream>>>(segtot, segbase);
  p1scat_k<<<NBLK, 512, 0, stream>>>(src, rank, rowpref, segbase, esort);
  p2_k<<<NSEGS, 256, 0, stream>>>(esort, segtot, segbase, s_sorted, ptr, dinv);

  // layer 1 reordered: xhat = A_norm*x (bf16), hout = relu(BN(xhat@W1+b1)) in GEMM epilogue
  agg_x_k<<<(NNODES + 3) / 4, 256, 0, stream>>>(ptr, s_sorted, dinv, xbf, xhHi, NNODES);
  gemm_split_k<128, 1, false><<<dim3((NNODES + 127) / 128, HDIM / 128), 256, 0, stream>>>(
      xhHi, nullptr, w1thi, w1tlo, nullptr, houtHi, bn_s, bn_t, NNODES, HDIM, FIN);

  // layer 2: h2 = hout@W2 (2-term), out = A_norm*h2 + b2
  gemm_split_k<64, 2, false><<<dim3((NNODES + 127) / 128, 1), 256, 0, stream>>>(
      houtHi, nullptr, w2thi, w2tlo, h2, h2bf, nullptr, nullptr, NNODES, CDIM, HDIM);
  agg2_k<<<(NNODES + 3) / 4, 256, 0, stream>>>(ptr, s_sorted, dinv, h2, h2bf, b2, out, NNODES);
}